// Round 16
// baseline (427.744 us; speedup 1.0000x reference)
//
#include <hip/hip_runtime.h>
#include <hip/hip_bf16.h>

typedef __bf16 bf16;
typedef __bf16 bf16x8 __attribute__((ext_vector_type(8)));
typedef __bf16 bf16x4 __attribute__((ext_vector_type(4)));
typedef float f32x4 __attribute__((ext_vector_type(4)));
typedef float f32x16 __attribute__((ext_vector_type(16)));
typedef unsigned int uint;

#define NB 4
#define NS 2048
#define ND 1024
#define NHH 16
#define NHD 64

__device__ __forceinline__ void gload_lds16(const void* g, void* l) {
  __builtin_amdgcn_global_load_lds((const __attribute__((address_space(1))) void*)g,
                                   (__attribute__((address_space(3))) void*)l, 16, 0, 0);
}

__device__ __forceinline__ f32x4 mfma16(bf16x8 a, bf16x8 b, f32x4 c) {
  return __builtin_amdgcn_mfma_f32_16x16x32_bf16(a, b, c, 0, 0, 0);
}
__device__ __forceinline__ f32x16 mfma32(bf16x8 a, bf16x8 b, f32x16 c) {
  return __builtin_amdgcn_mfma_f32_32x32x16_bf16(a, b, c, 0, 0, 0);
}
__device__ __forceinline__ uint cvtpk(float lo, float hi) {
  uint r;
  asm("v_cvt_pk_bf16_f32 %0, %1, %2" : "=v"(r) : "v"(lo), "v"(hi));
  return r;
}
__device__ __forceinline__ void swap32u(uint& a, uint& b) {
  asm("v_permlane32_swap_b32 %0, %1" : "+v"(a), "+v"(b));
}
__device__ __forceinline__ float expv(float x) {
  float r;
  asm("v_exp_f32 %0, %1" : "=v"(r) : "v"(x));
  return r;
}
#define BARRIER()                          \
  do {                                     \
    asm volatile("" ::: "memory");         \
    __builtin_amdgcn_s_barrier();          \
    asm volatile("" ::: "memory");         \
  } while (0)

// --- fused prep: 4 weights->bf16 | mask->bias | mask->packed clean bits ---
__global__ __launch_bounds__(256) void prep(
    const float4* __restrict__ w0, const float4* __restrict__ w1,
    const float4* __restrict__ w2, const float4* __restrict__ w3,
    bf16x4* __restrict__ wout, float scale0, int n4each,
    const int* __restrict__ m, float* __restrict__ mb,
    uint* __restrict__ cleanw, int nmask) {
  const int bid = blockIdx.x;
  if (bid < 4096) {
    int i = bid * 256 + threadIdx.x;
    int w = i / n4each;
    int j = i - w * n4each;
    const float4* src = (w == 0) ? w0 : (w == 1) ? w1 : (w == 2) ? w2 : w3;
    float sc = (w == 0) ? scale0 : 1.0f;
    float4 v = src[j];
    bf16x4 o;
    o[0] = (bf16)(v.x * sc);
    o[1] = (bf16)(v.y * sc);
    o[2] = (bf16)(v.z * sc);
    o[3] = (bf16)(v.w * sc);
    wout[i] = o;
  } else if (bid < 4128) {
    int i = (bid - 4096) * 256 + threadIdx.x;
    if (i < nmask) mb[i] = m[i] ? 0.0f : -3e38f;
  } else {
    int i = threadIdx.x;
    if (i < 128) {
      const int* p = m + i * 64;
      int all1 = 1;
#pragma unroll
      for (int j = 0; j < 64; j += 4) {
        int4 v = *(const int4*)(p + j);
        all1 &= (v.x && v.y && v.z && v.w) ? 1 : 0;
      }
      unsigned long long bal = __ballot(all1);
      int wv = i >> 6, lane = i & 63;
      if (lane == 0) {
        cleanw[2 * wv] = (uint)bal;
        cleanw[2 * wv + 1] = (uint)(bal >> 32);
      }
    }
  }
}

// ---- fused QKV projection: {Q,K,V} = f32-X @ W^T, one launch ----
// grid 1536 = 3z x (64 rowtiles x 8 coltiles), XCD-chunk swizzle.
// Tile 128x128, 4 waves 2x2, acc[4][4]; BK=32, 32 K-steps.
// A (f32 input): NO LDS -- per-lane direct fragment loads (frag m = row
//   wr*64+m*16+r, cols 8g..8g+7 -> 2 float4), parity ping-pong reg sets
//   (aE even tiles / aO odd), depth-2, consume(cvt)-then-refill.
// B: R14-proven 3-buffer gload_lds rotation + R15 slot swizzle.
// Counted wait: per iter one 10-load group (8 A + 2 B) is issued; at iter t
// vmcnt(10) leaves only t+1's group outstanding => tile-t loads (issued at
// t-2) landed. Loads are confined between BARRIER()s (memory clobber), so
// the group count per window is exact. z==2 writes V transposed.
__global__ __launch_bounds__(256) void gemm_qkv(
    const float* __restrict__ Aq, const float* __restrict__ Ak,
    const float* __restrict__ Av, const bf16* __restrict__ Wb,
    bf16* __restrict__ Qb, bf16* __restrict__ Kb, bf16* __restrict__ Vtb) {
  __shared__ bf16 Bs[3][4096];
  bf16* Bs0 = &Bs[0][0];
  const int tid = threadIdx.x;
  const int lane = tid & 63, wv = tid >> 6;
  const int wr = wv >> 1, wc = wv & 1;
  const int g = lane >> 4, r = lane & 15;
  const int bid = blockIdx.x;
  const int wg = (bid & 7) * 192 + (bid >> 3);  // 1536 = 8*192, bijective
  const int z = wg >> 9;
  const int t5 = wg & 511;
  const int colBase = (t5 & 7) * 128;
  const int rowBase = (t5 >> 3) * 128;

  const float* A = (z == 0) ? Aq : (z == 1) ? Ak : Av;
  const bf16* Bw = Wb + (long)z * ND * ND;

  // A fragment bases (per-lane): frag m = row wr*64+m*16+r, col 8g
  const float* a0p = A + (long)(rowBase + wr * 64 + 0 * 16 + r) * ND + 8 * g;
  const float* a1p = A + (long)(rowBase + wr * 64 + 1 * 16 + r) * ND + 8 * g;
  const float* a2p = A + (long)(rowBase + wr * 64 + 2 * 16 + r) * ND + 8 * g;
  const float* a3p = A + (long)(rowBase + wr * 64 + 3 * 16 + r) * ND + 8 * g;

  // B staging (source slot pre-swizzle, linear LDS dest)
  const int sRow = wv * 16 + (lane >> 2);
  const int sK = ((lane & 3) ^ ((lane >> 3) & 3)) * 8;
  const bf16* bj0 = Bw + (long)(colBase + sRow) * ND + sK;
  const bf16* bj1 = bj0 + 64L * ND;

#define ALOAD(S, kk)                       \
  do {                                     \
    S[0] = *(const float4*)(a0p + (kk));   \
    S[1] = *(const float4*)(a0p + (kk) + 4); \
    S[2] = *(const float4*)(a1p + (kk));   \
    S[3] = *(const float4*)(a1p + (kk) + 4); \
    S[4] = *(const float4*)(a2p + (kk));   \
    S[5] = *(const float4*)(a2p + (kk) + 4); \
    S[6] = *(const float4*)(a3p + (kk));   \
    S[7] = *(const float4*)(a3p + (kk) + 4); \
  } while (0)
#define BSTAGE(bi, kk)                                           \
  do {                                                           \
    gload_lds16(bj0 + (kk), Bs0 + (bi) * 4096 + wv * 512);       \
    gload_lds16(bj1 + (kk), Bs0 + (bi) * 4096 + 2048 + wv * 512); \
  } while (0)
#define ACVT(S)                                                  \
  do {                                                           \
    _Pragma("unroll") for (int m = 0; m < 4; m++) {              \
      af[m][0] = (bf16)S[2 * m].x;                               \
      af[m][1] = (bf16)S[2 * m].y;                               \
      af[m][2] = (bf16)S[2 * m].z;                               \
      af[m][3] = (bf16)S[2 * m].w;                               \
      af[m][4] = (bf16)S[2 * m + 1].x;                           \
      af[m][5] = (bf16)S[2 * m + 1].y;                           \
      af[m][6] = (bf16)S[2 * m + 1].z;                           \
      af[m][7] = (bf16)S[2 * m + 1].w;                           \
    }                                                            \
  } while (0)
#define QKV_STEP(S)                                              \
  do {                                                           \
    if (t == 31)                                                 \
      asm volatile("s_waitcnt vmcnt(0)" ::: "memory");           \
    else                                                         \
      asm volatile("s_waitcnt vmcnt(10)" ::: "memory");          \
    BARRIER();                                                   \
    __builtin_amdgcn_sched_barrier(0);                           \
    bf16x8 af[4];                                                \
    ACVT(S); /* consume before refill (WAR via program order) */ \
    if (t + 2 < 32) {                                            \
      ALOAD(S, (t + 2) * 32);                                    \
      BSTAGE(nxt2, (t + 2) * 32);                                \
    }                                                            \
    __builtin_amdgcn_sched_barrier(0);                           \
    const bf16* Bc = Bs0 + cur * 4096;                           \
    __builtin_amdgcn_s_setprio(1);                               \
    _Pragma("unroll") for (int n = 0; n < 4; n++) {              \
      bf16x8 bfr = *(const bf16x8*)(Bc + (wc * 64 + n * 16 + r) * 32 + gs); \
      _Pragma("unroll") for (int m = 0; m < 4; m++)              \
          acc[m][n] = mfma16(af[m], bfr, acc[m][n]);             \
    }                                                            \
    __builtin_amdgcn_s_setprio(0);                               \
    cur = (cur == 2) ? 0 : cur + 1;                              \
    nxt2 = (nxt2 == 2) ? 0 : nxt2 + 1;                           \
    t++;                                                         \
  } while (0)

  f32x4 acc[4][4] = {};
  const int gs = (g ^ ((r >> 1) & 3)) * 8;  // swizzled read slot
  float4 aE[8], aO[8];

  // prologue: groups for tiles 0 (aE) and 1 (aO) in flight
  ALOAD(aE, 0);
  BSTAGE(0, 0);
  ALOAD(aO, 32);
  BSTAGE(1, 32);
  int cur = 0, nxt2 = 2, t = 0;

  for (int i = 0; i < 16; i++) {
    QKV_STEP(aE);  // even tile
    QKV_STEP(aO);  // odd tile
  }
#undef QKV_STEP
#undef ACVT
#undef BSTAGE
#undef ALOAD

  if (z <= 1) {
    bf16* C = z ? Kb : Qb;
#pragma unroll
    for (int m = 0; m < 4; m++)
#pragma unroll
      for (int n = 0; n < 4; n++)
#pragma unroll
        for (int q = 0; q < 4; q++) {
          int row = rowBase + wr * 64 + m * 16 + 4 * g + q;
          int col = colBase + wc * 64 + n * 16 + r;
          C[(long)row * ND + col] = (bf16)acc[m][n][q];
        }
  } else {
    // V transposed: Vt[bh][d][s]; s = (rowBase&2047) + wr*64 + m*16 + 4g + q
    const int b = rowBase >> 11;
    const int sbase = (rowBase & 2047) + wr * 64;
#pragma unroll
    for (int m = 0; m < 4; m++) {
#pragma unroll
      for (int n = 0; n < 4; n++) {
        int col = colBase + wc * 64 + n * 16 + r;
        int h = col >> 6, d = col & 63;
        bf16x4 pk;
#pragma unroll
        for (int q = 0; q < 4; q++) pk[q] = (bf16)acc[m][n][q];
        *(bf16x4*)(Vtb + ((long)(b * NHH + h) * NHD + d) * NS + sbase + m * 16 + 4 * g) = pk;
      }
    }
  }
}

// ---- unified 128x128 bf16 GEMM, C = A @ B^T (R15-proven; EPI=2 used) ----
template <int EPI>
__global__ __launch_bounds__(256) void gemm8(
    const bf16* __restrict__ A, const bf16* __restrict__ Bw,
    bf16* __restrict__ Cb, float* __restrict__ Cf,
    const float* __restrict__ bias, int M, int N, int K) {
  __shared__ bf16 As[3][4096];
  __shared__ bf16 Bs[3][4096];
  bf16* As0 = &As[0][0];
  bf16* Bs0 = &Bs[0][0];
  const int tid = threadIdx.x;
  const int lane = tid & 63, wv = tid >> 6;
  const int wr = wv >> 1, wc = wv & 1;
  const int g = lane >> 4, r = lane & 15;
  const int nx = N >> 7;
  const int chunk = gridDim.x >> 3;
  const int bid = blockIdx.x;
  const int wg = (bid & 7) * chunk + (bid >> 3);
  const int colBase = (wg % nx) * 128;
  const int rowBase = (wg / nx) * 128;

  const int sRow = wv * 16 + (lane >> 2);
  const int sK = ((lane & 3) ^ ((lane >> 3) & 3)) * 8;
  const bf16* aj0 = A + (long)(rowBase + sRow) * K + sK;
  const bf16* aj1 = aj0 + 64L * K;
  const bf16* bj0 = Bw + (long)(colBase + sRow) * K + sK;
  const bf16* bj1 = bj0 + 64L * K;

#define GSTAGE(bi, kk)                                      \
  do {                                                      \
    gload_lds16(aj0 + (kk), As0 + (bi) * 4096 + wv * 512);  \
    gload_lds16(aj1 + (kk), As0 + (bi) * 4096 + 2048 + wv * 512); \
    gload_lds16(bj0 + (kk), Bs0 + (bi) * 4096 + wv * 512);  \
    gload_lds16(bj1 + (kk), Bs0 + (bi) * 4096 + 2048 + wv * 512); \
  } while (0)

  f32x4 acc[4][4] = {};
  const int gs = (g ^ ((r >> 1) & 3)) * 8;

  GSTAGE(0, 0);
  GSTAGE(1, 32);
  int cur = 0, nxt2 = 2;

  for (int k0 = 0; k0 < K; k0 += 32) {
    if (k0 + 32 < K) {
      asm volatile("s_waitcnt vmcnt(4)" ::: "memory");
    } else {
      asm volatile("s_waitcnt vmcnt(0)" ::: "memory");
    }
    BARRIER();
    __builtin_amdgcn_sched_barrier(0);
    if (k0 + 64 < K) GSTAGE(nxt2, k0 + 64);

    const bf16* Ac = As0 + cur * 4096;
    const bf16* Bc = Bs0 + cur * 4096;
    bf16x8 af[4], bfr[4];
#pragma unroll
    for (int m = 0; m < 4; m++)
      af[m] = *(const bf16x8*)(Ac + (wr * 64 + m * 16 + r) * 32 + gs);
#pragma unroll
    for (int n = 0; n < 4; n++)
      bfr[n] = *(const bf16x8*)(Bc + (wc * 64 + n * 16 + r) * 32 + gs);
    __builtin_amdgcn_s_setprio(1);
#pragma unroll
    for (int m = 0; m < 4; m++)
#pragma unroll
      for (int n = 0; n < 4; n++)
        acc[m][n] = mfma16(af[m], bfr[n], acc[m][n]);
    __builtin_amdgcn_s_setprio(0);
    cur = (cur == 2) ? 0 : cur + 1;
    nxt2 = (nxt2 == 2) ? 0 : nxt2 + 1;
  }
#undef GSTAGE

  if (EPI == 0) {
#pragma unroll
    for (int m = 0; m < 4; m++)
#pragma unroll
      for (int n = 0; n < 4; n++)
#pragma unroll
        for (int q = 0; q < 4; q++) {
          int row = rowBase + wr * 64 + m * 16 + 4 * g + q;
          int col = colBase + wc * 64 + n * 16 + r;
          Cb[(long)row * N + col] = (bf16)acc[m][n][q];
        }
  } else {
#pragma unroll
    for (int m = 0; m < 4; m++)
#pragma unroll
      for (int n = 0; n < 4; n++)
#pragma unroll
        for (int q = 0; q < 4; q++) {
          int row = rowBase + wr * 64 + m * 16 + 4 * g + q;
          int col = colBase + wc * 64 + n * 16 + r;
          float v = acc[m][n][q] + bias[col];
          v = 0.5f * v * (1.0f + erff(v * 0.70710678118654752f));
          Cf[(long)row * N + col] = v;
        }
  }
}

// ------- flash attention: 8-wave, swapped-operand, shift-free softmax ----
// (R15-proven; denominator via ones-row PV MFMA.)
__global__ __launch_bounds__(512) void attn_fwd4(
    const bf16* __restrict__ Q, const bf16* __restrict__ K,
    const bf16* __restrict__ Vt, const float* __restrict__ mbias,
    const uint* __restrict__ cleanw, bf16* __restrict__ ctx) {
  __shared__ bf16 Ks[3][64 * 64];
  __shared__ bf16 Vs[3][64 * 64];
  bf16* Ks0 = &Ks[0][0];
  bf16* Vs0 = &Vs[0][0];
  const int tid = threadIdx.x;
  const int lane = tid & 63, wv = tid >> 6;
  const int ql = lane & 31, hi = lane >> 5;
  const int g = blockIdx.x;
  const int gx = (g & 63) >> 3;
  const int bh = ((g >> 6) << 3) | (g & 7);
  const int b = bh >> 4, h = bh & 15;
  const int q0 = gx * 256 + wv * 32;

  const bf16* Qp = Q + ((long)(b * NS + q0 + ql)) * ND + h * NHD;
  const bf16* Kp = K + ((long)b * NS) * ND + h * NHD;
  const bf16* Vp = Vt + (long)bh * NHD * NS;
  const float* mbp = mbias + b * NS;
  const uint cw = cleanw[b];

  bf16x8 qf[4];
#pragma unroll
  for (int cd = 0; cd < 4; cd++)
    qf[cd] = *(const bf16x8*)(Qp + cd * 16 + hi * 8);

  bf16x8 ones;
#pragma unroll
  for (int i = 0; i < 8; i++) ones[i] = (bf16)1.0f;

  f32x16 o[2] = {};
  f32x16 ldn = {};

  const int Lrow = wv * 8 + (lane >> 3);
  const int scb = ((lane & 7) * 16) ^ ((Lrow & 7) << 4);
  const bf16* kS = Kp + (long)Lrow * ND + (scb >> 1);
  const bf16* vS = Vp + (long)Lrow * NS + (scb >> 1);

#define ASTAGE(bi, sv)                                        \
  do {                                                        \
    gload_lds16(kS + (long)(sv) * ND, Ks0 + (bi) * 4096 + wv * 512); \
    gload_lds16(vS + (sv), Vs0 + (bi) * 4096 + wv * 512);     \
  } while (0)

  const int swz = (ql & 7) << 4;

  ASTAGE(0, 0);
  int cur = 0, nxt = 1;

  for (int s0 = 0; s0 < NS; s0 += 64) {
    if (s0 + 64 < NS) {
      ASTAGE(nxt, s0 + 64);
      asm volatile("s_waitcnt vmcnt(2)" ::: "memory");
    } else {
      asm volatile("s_waitcnt vmcnt(0)" ::: "memory");
    }
    BARRIER();
    __builtin_amdgcn_sched_barrier(0);
    const char* KsB = (const char*)(Ks0 + cur * 4096);
    const char* VsB = (const char*)(Vs0 + cur * 4096);

    f32x16 st0 = {}, st1 = {};
    __builtin_amdgcn_s_setprio(1);
#pragma unroll
    for (int cd = 0; cd < 4; cd++) {
      bf16x8 kf0 = *(const bf16x8*)(KsB + ql * 128 + ((cd * 32 + hi * 16) ^ swz));
      st0 = mfma32(kf0, qf[cd], st0);
      bf16x8 kf1 = *(const bf16x8*)(KsB + (32 + ql) * 128 + ((cd * 32 + hi * 16) ^ swz));
      st1 = mfma32(kf1, qf[cd], st1);
    }
    __builtin_amdgcn_s_setprio(0);

    if (!((cw >> (s0 >> 6)) & 1)) {
#pragma unroll
      for (int t = 0; t < 4; t++) {
        float4 m0 = *(const float4*)(mbp + s0 + t * 8 + hi * 4);
        st0[4 * t + 0] += m0.x;
        st0[4 * t + 1] += m0.y;
        st0[4 * t + 2] += m0.z;
        st0[4 * t + 3] += m0.w;
        float4 m1 = *(const float4*)(mbp + s0 + 32 + t * 8 + hi * 4);
        st1[4 * t + 0] += m1.x;
        st1[4 * t + 1] += m1.y;
        st1[4 * t + 2] += m1.z;
        st1[4 * t + 3] += m1.w;
      }
    }

#pragma unroll
    for (int i = 0; i < 16; i++) {
      st0[i] = expv(st0[i]);
      st1[i] = expv(st1[i]);
    }

    union {
      uint u[16];
      bf16x8 f[4];
    } pw;
    {
      uint c0 = cvtpk(st0[0], st0[1]), c1 = cvtpk(st0[4], st0[5]);
      swap32u(c0, c1);
      uint d0 = cvtpk(st0[2], st0[3]), d1 = cvtpk(st0[6], st0[7]);
      swap32u(d0, d1);
      pw.u[0] = c0; pw.u[1] = d0; pw.u[2] = c1; pw.u[3] = d1;
      uint e0 = cvtpk(st0[8], st0[9]), e1 = cvtpk(st0[12], st0[13]);
      swap32u(e0, e1);
      uint f0 = cvtpk(st0[10], st0[11]), f1 = cvtpk(st0[14], st0[15]);
      swap32u(f0, f1);
      pw.u[4] = e0; pw.u[5] = f0; pw.u[6] = e1; pw.u[7] = f1;
    }
    {
      uint c0 = cvtpk(st1[0], st1[1]), c1 = cvtpk(st1[4], st1[5]);
      swap32u(c0, c1);
      uint d0 = cvtpk(st1[2], st1[3]), d1 = cvtpk(st1[6], st1[7]);
      swap32u(d0, d1);
      pw.u[8] = c0; pw.u[9] = d0; pw.u[10] = c1; pw.u[11] = d1;
      uint e0 = cvtpk(st1[8], st1[9]), e1 = cvtpk(st1[12], st1[13]);
      swap32u(e0, e1);
      uint f0 = cvtpk(st1[10], st1[11]), f1 = cvtpk(st1[14], st1[15]);
      swap32u(f0, f1);
      pw.u[12] = e0; pw.u[13] = f0; pw.u[14] = e1; pw.u[15] = f1;
    }

    __builtin_amdgcn_s_setprio(1);
#pragma unroll
    for (int dt = 0; dt < 2; dt++) {
#pragma unroll
      for (int ck = 0; ck < 4; ck++) {
        bf16x8 vf = *(const bf16x8*)(VsB + (dt * 32 + ql) * 128 +
                                     ((ck * 32 + hi * 16) ^ swz));
        o[dt] = mfma32(vf, pw.f[ck], o[dt]);
      }
    }
#pragma unroll
    for (int ck = 0; ck < 4; ck++) ldn = mfma32(ones, pw.f[ck], ldn);
    __builtin_amdgcn_s_setprio(0);
    cur = nxt;
    nxt = (nxt == 2) ? 0 : nxt + 1;
  }
#undef ASTAGE

  const float invL = 1.0f / ldn[0];
  bf16* op = ctx + ((long)(b * NS + q0 + ql)) * ND + h * NHD;
#pragma unroll
  for (int dt = 0; dt < 2; dt++) {
#pragma unroll
    for (int t = 0; t < 4; t++) {
      bf16x4 pk;
#pragma unroll
      for (int i = 0; i < 4; i++) pk[i] = (bf16)(o[dt][t * 4 + i] * invL);
      *(bf16x4*)(op + dt * 32 + t * 8 + hi * 4) = pk;
    }
  }
}

extern "C" void kernel_launch(void* const* d_in, const int* in_sizes, int n_in,
                              void* d_out, int out_size, void* d_ws, size_t ws_size,
                              hipStream_t stream) {
  const float* value = (const float*)d_in[0];
  const float* key_t = (const float*)d_in[1];
  const float* query = (const float*)d_in[2];
  const int* mask = (const int*)d_in[3];
  const float* W_q = (const float*)d_in[4];
  const float* W_k = (const float*)d_in[5];
  const float* W_v = (const float*)d_in[6];
  const float* W_o = (const float*)d_in[7];
  const float* b_o = (const float*)d_in[8];
  float* out = (float*)d_out;

  char* ws = (char*)d_ws;
  bf16* ctx = (bf16*)(ws + 0);               // 16MB (attn output)
  bf16* wb = (bf16*)(ws + (16UL << 20));     // 8MB: wq, wk, wv, wo
  bf16* Qb = (bf16*)(ws + (24UL << 20));     // 16MB
  bf16* Kb = (bf16*)(ws + (40UL << 20));     // 16MB
  bf16* Vtb = (bf16*)(ws + (56UL << 20));    // 16MB (pre-transposed V)
  float* mbias = (float*)(ws + (72UL << 20));
  uint* cleanwd = (uint*)(ws + (72UL << 20) + 32768);

  const int nW4 = (ND * ND) / 4;
  // HD^-0.5 * log2(e) folded into W_q -> logits in base-2 units
  const float hscale = 0.125f * 1.44269504088896f;

  prep<<<4129, 256, 0, stream>>>((const float4*)W_q, (const float4*)W_k,
                                 (const float4*)W_v, (const float4*)W_o,
                                 (bf16x4*)wb, hscale, nW4,
                                 mask, mbias, cleanwd, NB * NS);
  bf16* wob = wb + 3L * ND * ND;

  gemm_qkv<<<1536, 256, 0, stream>>>(query, key_t, value, wb, Qb, Kb, Vtb);

  attn_fwd4<<<512, 512, 0, stream>>>(Qb, Kb, Vtb, mbias, cleanwd, ctx);

  gemm8<2><<<((NB * NS) / 128) * (ND / 128), 256, 0, stream>>>(
      ctx, wob, nullptr, out, b_o, NB * NS, ND, ND);
}

// Round 17
// 220.065 us; speedup vs baseline: 1.9437x; 1.9437x over previous
//
#include <hip/hip_runtime.h>
#include <hip/hip_bf16.h>

typedef __bf16 bf16;
typedef __bf16 bf16x8 __attribute__((ext_vector_type(8)));
typedef __bf16 bf16x4 __attribute__((ext_vector_type(4)));
typedef float f32x4 __attribute__((ext_vector_type(4)));
typedef float f32x16 __attribute__((ext_vector_type(16)));
typedef unsigned int uint;

#define NB 4
#define NS 2048
#define ND 1024
#define NHH 16
#define NHD 64

__device__ __forceinline__ void gload_lds16(const void* g, void* l) {
  __builtin_amdgcn_global_load_lds((const __attribute__((address_space(1))) void*)g,
                                   (__attribute__((address_space(3))) void*)l, 16, 0, 0);
}

__device__ __forceinline__ f32x4 mfma16(bf16x8 a, bf16x8 b, f32x4 c) {
  return __builtin_amdgcn_mfma_f32_16x16x32_bf16(a, b, c, 0, 0, 0);
}
__device__ __forceinline__ f32x16 mfma32(bf16x8 a, bf16x8 b, f32x16 c) {
  return __builtin_amdgcn_mfma_f32_32x32x16_bf16(a, b, c, 0, 0, 0);
}
__device__ __forceinline__ uint cvtpk(float lo, float hi) {
  uint r;
  asm("v_cvt_pk_bf16_f32 %0, %1, %2" : "=v"(r) : "v"(lo), "v"(hi));
  return r;
}
__device__ __forceinline__ void swap32u(uint& a, uint& b) {
  asm("v_permlane32_swap_b32 %0, %1" : "+v"(a), "+v"(b));
}
__device__ __forceinline__ float expv(float x) {
  float r;
  asm("v_exp_f32 %0, %1" : "=v"(r) : "v"(x));
  return r;
}
#define BARRIER()                          \
  do {                                     \
    asm volatile("" ::: "memory");         \
    __builtin_amdgcn_s_barrier();          \
    asm volatile("" ::: "memory");         \
  } while (0)

// ---------------- f32 -> bf16 convert (one input) ----------------
__global__ __launch_bounds__(256) void cvt_bf16(const float4* __restrict__ in,
                                                bf16x4* __restrict__ out,
                                                float scale, int n4) {
  int i = blockIdx.x * 256 + threadIdx.x;
  if (i < n4) {
    float4 v = in[i];
    bf16x4 o;
    o[0] = (bf16)(v.x * scale);
    o[1] = (bf16)(v.y * scale);
    o[2] = (bf16)(v.z * scale);
    o[3] = (bf16)(v.w * scale);
    out[i] = o;
  }
}

// ---------------- f32 -> bf16 convert (two inputs, one launch) ----------
__global__ __launch_bounds__(256) void cvt2_bf16(const float4* __restrict__ inA,
                                                 bf16x4* __restrict__ outA,
                                                 const float4* __restrict__ inB,
                                                 bf16x4* __restrict__ outB,
                                                 int n4each) {
  int i = blockIdx.x * 256 + threadIdx.x;
  const float4* src = (i < n4each) ? inA : inB;
  bf16x4* dst = (i < n4each) ? outA : outB;
  int j = (i < n4each) ? i : i - n4each;
  float4 v = src[j];
  bf16x4 o;
  o[0] = (bf16)v.x;
  o[1] = (bf16)v.y;
  o[2] = (bf16)v.z;
  o[3] = (bf16)v.w;
  dst[j] = o;
}

// --- fused prep: 4 weights->bf16 | mask->bias | mask->packed clean bits ---
__global__ __launch_bounds__(256) void prep(
    const float4* __restrict__ w0, const float4* __restrict__ w1,
    const float4* __restrict__ w2, const float4* __restrict__ w3,
    bf16x4* __restrict__ wout, float scale0, int n4each,
    const int* __restrict__ m, float* __restrict__ mb,
    uint* __restrict__ cleanw, int nmask) {
  const int bid = blockIdx.x;
  if (bid < 4096) {
    int i = bid * 256 + threadIdx.x;
    int w = i / n4each;
    int j = i - w * n4each;
    const float4* src = (w == 0) ? w0 : (w == 1) ? w1 : (w == 2) ? w2 : w3;
    float sc = (w == 0) ? scale0 : 1.0f;
    float4 v = src[j];
    bf16x4 o;
    o[0] = (bf16)(v.x * sc);
    o[1] = (bf16)(v.y * sc);
    o[2] = (bf16)(v.z * sc);
    o[3] = (bf16)(v.w * sc);
    wout[i] = o;
  } else if (bid < 4128) {
    int i = (bid - 4096) * 256 + threadIdx.x;
    if (i < nmask) mb[i] = m[i] ? 0.0f : -3e38f;
  } else {
    int i = threadIdx.x;
    if (i < 128) {
      const int* p = m + i * 64;
      int all1 = 1;
#pragma unroll
      for (int j = 0; j < 64; j += 4) {
        int4 v = *(const int4*)(p + j);
        all1 &= (v.x && v.y && v.z && v.w) ? 1 : 0;
      }
      unsigned long long bal = __ballot(all1);
      int wv = i >> 6, lane = i & 63;
      if (lane == 0) {
        cleanw[2 * wv] = (uint)bal;
        cleanw[2 * wv + 1] = (uint)(bal >> 32);
      }
    }
  }
}

// ---- unified 128x128 bf16 GEMM, C = A @ B^T (R15-proven) ----
// 3-buffer depth-2 counted-vmcnt pipeline + both-sides LDS slot swizzle.
// EPI: 0 = bf16 C; 1 = V transposed to Vt[bh][d][s]; 2 = bias+erf-GELU f32.
template <int EPI>
__global__ __launch_bounds__(256) void gemm8(
    const bf16* __restrict__ A, const bf16* __restrict__ Bw,
    bf16* __restrict__ Cb, float* __restrict__ Cf,
    const float* __restrict__ bias, int M, int N, int K) {
  __shared__ bf16 As[3][4096];
  __shared__ bf16 Bs[3][4096];
  bf16* As0 = &As[0][0];
  bf16* Bs0 = &Bs[0][0];
  const int tid = threadIdx.x;
  const int lane = tid & 63, wv = tid >> 6;
  const int wr = wv >> 1, wc = wv & 1;
  const int g = lane >> 4, r = lane & 15;
  const int nx = N >> 7;
  const int chunk = gridDim.x >> 3;
  const int bid = blockIdx.x;
  const int wg = (bid & 7) * chunk + (bid >> 3);  // grid % 8 == 0: bijective
  const int colBase = (wg % nx) * 128;
  const int rowBase = (wg / nx) * 128;

  const int sRow = wv * 16 + (lane >> 2);
  const int sK = ((lane & 3) ^ ((lane >> 3) & 3)) * 8;  // source pre-swizzle
  const bf16* aj0 = A + (long)(rowBase + sRow) * K + sK;
  const bf16* aj1 = aj0 + 64L * K;
  const bf16* bj0 = Bw + (long)(colBase + sRow) * K + sK;
  const bf16* bj1 = bj0 + 64L * K;

#define GSTAGE(bi, kk)                                      \
  do {                                                      \
    gload_lds16(aj0 + (kk), As0 + (bi) * 4096 + wv * 512);  \
    gload_lds16(aj1 + (kk), As0 + (bi) * 4096 + 2048 + wv * 512); \
    gload_lds16(bj0 + (kk), Bs0 + (bi) * 4096 + wv * 512);  \
    gload_lds16(bj1 + (kk), Bs0 + (bi) * 4096 + 2048 + wv * 512); \
  } while (0)

  f32x4 acc[4][4] = {};
  const int gs = (g ^ ((r >> 1) & 3)) * 8;  // swizzled read slot

  GSTAGE(0, 0);
  GSTAGE(1, 32);
  int cur = 0, nxt2 = 2;  // buffer of tile t, buffer of tile t+2

  for (int k0 = 0; k0 < K; k0 += 32) {
    if (k0 + 32 < K) {
      asm volatile("s_waitcnt vmcnt(4)" ::: "memory");  // tile-t landed
    } else {
      asm volatile("s_waitcnt vmcnt(0)" ::: "memory");
    }
    BARRIER();  // all waves: tile-t staged; buf[nxt2] readers (t-1) retired
    __builtin_amdgcn_sched_barrier(0);
    if (k0 + 64 < K) GSTAGE(nxt2, k0 + 64);

    const bf16* Ac = As0 + cur * 4096;
    const bf16* Bc = Bs0 + cur * 4096;
    bf16x8 af[4], bfr[4];
#pragma unroll
    for (int m = 0; m < 4; m++)
      af[m] = *(const bf16x8*)(Ac + (wr * 64 + m * 16 + r) * 32 + gs);
#pragma unroll
    for (int n = 0; n < 4; n++)
      bfr[n] = *(const bf16x8*)(Bc + (wc * 64 + n * 16 + r) * 32 + gs);
    __builtin_amdgcn_s_setprio(1);
#pragma unroll
    for (int m = 0; m < 4; m++)
#pragma unroll
      for (int n = 0; n < 4; n++)
        acc[m][n] = mfma16(af[m], bfr[n], acc[m][n]);
    __builtin_amdgcn_s_setprio(0);
    cur = (cur == 2) ? 0 : cur + 1;
    nxt2 = (nxt2 == 2) ? 0 : nxt2 + 1;
  }
#undef GSTAGE

  if (EPI == 0) {
#pragma unroll
    for (int m = 0; m < 4; m++)
#pragma unroll
      for (int n = 0; n < 4; n++)
#pragma unroll
        for (int q = 0; q < 4; q++) {
          int row = rowBase + wr * 64 + m * 16 + 4 * g + q;
          int col = colBase + wc * 64 + n * 16 + r;
          Cb[(long)row * N + col] = (bf16)acc[m][n][q];
        }
  } else if (EPI == 1) {
    // V transposed: Vt[bh][d][s]; s = (rowBase&2047) + wr*64 + m*16 + 4g + q
    const int b = rowBase >> 11;
    const int sbase = (rowBase & 2047) + wr * 64;
#pragma unroll
    for (int m = 0; m < 4; m++) {
#pragma unroll
      for (int n = 0; n < 4; n++) {
        int col = colBase + wc * 64 + n * 16 + r;
        int h = col >> 6, d = col & 63;
        bf16x4 pk;
#pragma unroll
        for (int q = 0; q < 4; q++) pk[q] = (bf16)acc[m][n][q];
        *(bf16x4*)(Cb + ((long)(b * NHH + h) * NHD + d) * NS + sbase + m * 16 + 4 * g) = pk;
      }
    }
  } else {
#pragma unroll
    for (int m = 0; m < 4; m++)
#pragma unroll
      for (int n = 0; n < 4; n++)
#pragma unroll
        for (int q = 0; q < 4; q++) {
          int row = rowBase + wr * 64 + m * 16 + 4 * g + q;
          int col = colBase + wc * 64 + n * 16 + r;
          float v = acc[m][n][q] + bias[col];
          v = 0.5f * v * (1.0f + erff(v * 0.70710678118654752f));
          Cf[(long)row * N + col] = v;
        }
  }
}

// ------- flash attention: 8-wave, swapped-operand, shift-free softmax ----
// QBLK=256 (8 waves x 32 q-rows), KBLK=64. 3-buffer/1-barrier counted-vmcnt
// pipeline; vmcnt(2). grid 512, XCD-swizzled. Logits base-2: p = 2^st.
// Softmax denominator via ones-row PV MFMA (R15-proven).
__global__ __launch_bounds__(512) void attn_fwd4(
    const bf16* __restrict__ Q, const bf16* __restrict__ K,
    const bf16* __restrict__ Vt, const float* __restrict__ mbias,
    const uint* __restrict__ cleanw, bf16* __restrict__ ctx) {
  __shared__ bf16 Ks[3][64 * 64];
  __shared__ bf16 Vs[3][64 * 64];
  bf16* Ks0 = &Ks[0][0];
  bf16* Vs0 = &Vs[0][0];
  const int tid = threadIdx.x;
  const int lane = tid & 63, wv = tid >> 6;
  const int ql = lane & 31, hi = lane >> 5;
  const int g = blockIdx.x;
  const int gx = (g & 63) >> 3;
  const int bh = ((g >> 6) << 3) | (g & 7);
  const int b = bh >> 4, h = bh & 15;
  const int q0 = gx * 256 + wv * 32;

  const bf16* Qp = Q + ((long)(b * NS + q0 + ql)) * ND + h * NHD;
  const bf16* Kp = K + ((long)b * NS) * ND + h * NHD;
  const bf16* Vp = Vt + (long)bh * NHD * NS;
  const float* mbp = mbias + b * NS;
  const uint cw = cleanw[b];

  bf16x8 qf[4];
#pragma unroll
  for (int cd = 0; cd < 4; cd++)
    qf[cd] = *(const bf16x8*)(Qp + cd * 16 + hi * 8);

  bf16x8 ones;
#pragma unroll
  for (int i = 0; i < 8; i++) ones[i] = (bf16)1.0f;

  f32x16 o[2] = {};
  f32x16 ldn = {};

  const int Lrow = wv * 8 + (lane >> 3);
  const int scb = ((lane & 7) * 16) ^ ((Lrow & 7) << 4);
  const bf16* kS = Kp + (long)Lrow * ND + (scb >> 1);
  const bf16* vS = Vp + (long)Lrow * NS + (scb >> 1);

#define ASTAGE(bi, sv)                                        \
  do {                                                        \
    gload_lds16(kS + (long)(sv) * ND, Ks0 + (bi) * 4096 + wv * 512); \
    gload_lds16(vS + (sv), Vs0 + (bi) * 4096 + wv * 512);     \
  } while (0)

  const int swz = (ql & 7) << 4;

  ASTAGE(0, 0);
  int cur = 0, nxt = 1;

  for (int s0 = 0; s0 < NS; s0 += 64) {
    if (s0 + 64 < NS) {
      ASTAGE(nxt, s0 + 64);
      asm volatile("s_waitcnt vmcnt(2)" ::: "memory");
    } else {
      asm volatile("s_waitcnt vmcnt(0)" ::: "memory");
    }
    BARRIER();
    __builtin_amdgcn_sched_barrier(0);
    const char* KsB = (const char*)(Ks0 + cur * 4096);
    const char* VsB = (const char*)(Vs0 + cur * 4096);

    f32x16 st0 = {}, st1 = {};
    __builtin_amdgcn_s_setprio(1);
#pragma unroll
    for (int cd = 0; cd < 4; cd++) {
      bf16x8 kf0 = *(const bf16x8*)(KsB + ql * 128 + ((cd * 32 + hi * 16) ^ swz));
      st0 = mfma32(kf0, qf[cd], st0);
      bf16x8 kf1 = *(const bf16x8*)(KsB + (32 + ql) * 128 + ((cd * 32 + hi * 16) ^ swz));
      st1 = mfma32(kf1, qf[cd], st1);
    }
    __builtin_amdgcn_s_setprio(0);

    if (!((cw >> (s0 >> 6)) & 1)) {
#pragma unroll
      for (int t = 0; t < 4; t++) {
        float4 m0 = *(const float4*)(mbp + s0 + t * 8 + hi * 4);
        st0[4 * t + 0] += m0.x;
        st0[4 * t + 1] += m0.y;
        st0[4 * t + 2] += m0.z;
        st0[4 * t + 3] += m0.w;
        float4 m1 = *(const float4*)(mbp + s0 + 32 + t * 8 + hi * 4);
        st1[4 * t + 0] += m1.x;
        st1[4 * t + 1] += m1.y;
        st1[4 * t + 2] += m1.z;
        st1[4 * t + 3] += m1.w;
      }
    }

    // ---- shift-free softmax: p = 2^st ----
#pragma unroll
    for (int i = 0; i < 16; i++) {
      st0[i] = expv(st0[i]);
      st1[i] = expv(st1[i]);
    }

    // ---- P -> bf16 B-fragments (T12) ----
    union {
      uint u[16];
      bf16x8 f[4];
    } pw;
    {
      uint c0 = cvtpk(st0[0], st0[1]), c1 = cvtpk(st0[4], st0[5]);
      swap32u(c0, c1);
      uint d0 = cvtpk(st0[2], st0[3]), d1 = cvtpk(st0[6], st0[7]);
      swap32u(d0, d1);
      pw.u[0] = c0; pw.u[1] = d0; pw.u[2] = c1; pw.u[3] = d1;
      uint e0 = cvtpk(st0[8], st0[9]), e1 = cvtpk(st0[12], st0[13]);
      swap32u(e0, e1);
      uint f0 = cvtpk(st0[10], st0[11]), f1 = cvtpk(st0[14], st0[15]);
      swap32u(f0, f1);
      pw.u[4] = e0; pw.u[5] = f0; pw.u[6] = e1; pw.u[7] = f1;
    }
    {
      uint c0 = cvtpk(st1[0], st1[1]), c1 = cvtpk(st1[4], st1[5]);
      swap32u(c0, c1);
      uint d0 = cvtpk(st1[2], st1[3]), d1 = cvtpk(st1[6], st1[7]);
      swap32u(d0, d1);
      pw.u[8] = c0; pw.u[9] = d0; pw.u[10] = c1; pw.u[11] = d1;
      uint e0 = cvtpk(st1[8], st1[9]), e1 = cvtpk(st1[12], st1[13]);
      swap32u(e0, e1);
      uint f0 = cvtpk(st1[10], st1[11]), f1 = cvtpk(st1[14], st1[15]);
      swap32u(f0, f1);
      pw.u[12] = e0; pw.u[13] = f0; pw.u[14] = e1; pw.u[15] = f1;
    }

    // ---- O^T += V^T P^T ; denominator += ones^T P^T ----
    __builtin_amdgcn_s_setprio(1);
#pragma unroll
    for (int dt = 0; dt < 2; dt++) {
#pragma unroll
      for (int ck = 0; ck < 4; ck++) {
        bf16x8 vf = *(const bf16x8*)(VsB + (dt * 32 + ql) * 128 +
                                     ((ck * 32 + hi * 16) ^ swz));
        o[dt] = mfma32(vf, pw.f[ck], o[dt]);
      }
    }
#pragma unroll
    for (int ck = 0; ck < 4; ck++) ldn = mfma32(ones, pw.f[ck], ldn);
    __builtin_amdgcn_s_setprio(0);
    cur = nxt;
    nxt = (nxt == 2) ? 0 : nxt + 1;
  }
#undef ASTAGE

  const float invL = 1.0f / ldn[0];  // every ldn row = full sum over k
  bf16* op = ctx + ((long)(b * NS + q0 + ql)) * ND + h * NHD;
#pragma unroll
  for (int dt = 0; dt < 2; dt++) {
#pragma unroll
    for (int t = 0; t < 4; t++) {
      bf16x4 pk;
#pragma unroll
      for (int i = 0; i < 4; i++) pk[i] = (bf16)(o[dt][t * 4 + i] * invL);
      *(bf16x4*)(op + dt * 32 + t * 8 + hi * 4) = pk;
    }
  }
}

extern "C" void kernel_launch(void* const* d_in, const int* in_sizes, int n_in,
                              void* d_out, int out_size, void* d_ws, size_t ws_size,
                              hipStream_t stream) {
  const float* value = (const float*)d_in[0];
  const float* key_t = (const float*)d_in[1];
  const float* query = (const float*)d_in[2];
  const int* mask = (const int*)d_in[3];
  const float* W_q = (const float*)d_in[4];
  const float* W_k = (const float*)d_in[5];
  const float* W_v = (const float*)d_in[6];
  const float* W_o = (const float*)d_in[7];
  const float* b_o = (const float*)d_in[8];
  float* out = (float*)d_out;

  char* ws = (char*)d_ws;
  bf16* Axb = (bf16*)(ws + 0);               // 16MB: query-bf16, later value-bf16, later ctx
  bf16* ctx = (bf16*)(ws + 0);
  bf16* wb = (bf16*)(ws + (16UL << 20));     // 8MB: wq, wk, wv, wo
  bf16* Qb = (bf16*)(ws + (24UL << 20));     // 16MB
  bf16* Kb = (bf16*)(ws + (40UL << 20));     // 16MB
  bf16* Vtb = (bf16*)(ws + (56UL << 20));    // 16MB (pre-transposed V)
  bf16* Akb = (bf16*)(ws + (72UL << 20));    // 16MB: key-bf16 (dead after gemmK)
  float* mbias = (float*)(ws + (88UL << 20));          // R10-proven addresses
  uint* cleanwd = (uint*)(ws + (88UL << 20) + 32768);

  const int nX4 = (NB * NS * ND) / 4;  // 2M float4
  const int nW4 = (ND * ND) / 4;
  // HD^-0.5 * log2(e) folded into W_q -> logits in base-2 units
  const float hscale = 0.125f * 1.44269504088896f;

  prep<<<4129, 256, 0, stream>>>((const float4*)W_q, (const float4*)W_k,
                                 (const float4*)W_v, (const float4*)W_o,
                                 (bf16x4*)wb, hscale, nW4,
                                 mask, mbias, cleanwd, NB * NS);
  bf16* wqb = wb;
  bf16* wkb = wb + 1L * ND * ND;
  bf16* wvb = wb + 2L * ND * ND;
  bf16* wob = wb + 3L * ND * ND;

  const int ggrid = ((NB * NS) / 128) * (ND / 128);  // 64 * 8 = 512

  // query + key converted in ONE launch; Q/K gemms then run back-to-back
  cvt2_bf16<<<2 * nX4 / 256, 256, 0, stream>>>((const float4*)query, (bf16x4*)Axb,
                                               (const float4*)key_t, (bf16x4*)Akb, nX4);
  gemm8<0><<<ggrid, 256, 0, stream>>>(Axb, wqb, Qb, nullptr, nullptr, NB * NS, ND, ND);
  gemm8<0><<<ggrid, 256, 0, stream>>>(Akb, wkb, Kb, nullptr, nullptr, NB * NS, ND, ND);

  cvt_bf16<<<nX4 / 256, 256, 0, stream>>>((const float4*)value, (bf16x4*)Axb, 1.0f, nX4);
  gemm8<1><<<ggrid, 256, 0, stream>>>(Axb, wvb, Vtb, nullptr, nullptr, NB * NS, ND, ND);

  attn_fwd4<<<512, 512, 0, stream>>>(Qb, Kb, Vtb, mbias, cleanwd, ctx);

  gemm8<2><<<ggrid, 256, 0, stream>>>(ctx, wob, nullptr, out, b_o, NB * NS, ND, ND);
}

// Round 18
// 219.577 us; speedup vs baseline: 1.9480x; 1.0022x over previous
//
#include <hip/hip_runtime.h>
#include <hip/hip_bf16.h>

typedef __bf16 bf16;
typedef __bf16 bf16x8 __attribute__((ext_vector_type(8)));
typedef __bf16 bf16x4 __attribute__((ext_vector_type(4)));
typedef float f32x4 __attribute__((ext_vector_type(4)));
typedef float f32x16 __attribute__((ext_vector_type(16)));
typedef unsigned int uint;

#define NB 4
#define NS 2048
#define ND 1024
#define NHH 16
#define NHD 64

__device__ __forceinline__ void gload_lds16(const void* g, void* l) {
  __builtin_amdgcn_global_load_lds((const __attribute__((address_space(1))) void*)g,
                                   (__attribute__((address_space(3))) void*)l, 16, 0, 0);
}

__device__ __forceinline__ f32x4 mfma16(bf16x8 a, bf16x8 b, f32x4 c) {
  return __builtin_amdgcn_mfma_f32_16x16x32_bf16(a, b, c, 0, 0, 0);
}
__device__ __forceinline__ f32x16 mfma32(bf16x8 a, bf16x8 b, f32x16 c) {
  return __builtin_amdgcn_mfma_f32_32x32x16_bf16(a, b, c, 0, 0, 0);
}
__device__ __forceinline__ uint cvtpk(float lo, float hi) {
  uint r;
  asm("v_cvt_pk_bf16_f32 %0, %1, %2" : "=v"(r) : "v"(lo), "v"(hi));
  return r;
}
__device__ __forceinline__ void swap32u(uint& a, uint& b) {
  asm("v_permlane32_swap_b32 %0, %1" : "+v"(a), "+v"(b));
}
__device__ __forceinline__ float expv(float x) {
  float r;
  asm("v_exp_f32 %0, %1" : "=v"(r) : "v"(x));
  return r;
}
#define BARRIER()                          \
  do {                                     \
    asm volatile("" ::: "memory");         \
    __builtin_amdgcn_s_barrier();          \
    asm volatile("" ::: "memory");         \
  } while (0)

// ---------------- f32 -> bf16 convert (one input) ----------------
__global__ __launch_bounds__(256) void cvt_bf16(const float4* __restrict__ in,
                                                bf16x4* __restrict__ out,
                                                float scale, int n4) {
  int i = blockIdx.x * 256 + threadIdx.x;
  if (i < n4) {
    float4 v = in[i];
    bf16x4 o;
    o[0] = (bf16)(v.x * scale);
    o[1] = (bf16)(v.y * scale);
    o[2] = (bf16)(v.z * scale);
    o[3] = (bf16)(v.w * scale);
    out[i] = o;
  }
}

// ---------------- f32 -> bf16 convert (two inputs, one launch) ----------
__global__ __launch_bounds__(256) void cvt2_bf16(const float4* __restrict__ inA,
                                                 bf16x4* __restrict__ outA,
                                                 const float4* __restrict__ inB,
                                                 bf16x4* __restrict__ outB,
                                                 int n4each) {
  int i = blockIdx.x * 256 + threadIdx.x;
  const float4* src = (i < n4each) ? inA : inB;
  bf16x4* dst = (i < n4each) ? outA : outB;
  int j = (i < n4each) ? i : i - n4each;
  float4 v = src[j];
  bf16x4 o;
  o[0] = (bf16)v.x;
  o[1] = (bf16)v.y;
  o[2] = (bf16)v.z;
  o[3] = (bf16)v.w;
  dst[j] = o;
}

// --- fused prep: 4 weights->bf16 | mask->bias | mask->packed clean bits ---
__global__ __launch_bounds__(256) void prep(
    const float4* __restrict__ w0, const float4* __restrict__ w1,
    const float4* __restrict__ w2, const float4* __restrict__ w3,
    bf16x4* __restrict__ wout, float scale0, int n4each,
    const int* __restrict__ m, float* __restrict__ mb,
    uint* __restrict__ cleanw, int nmask) {
  const int bid = blockIdx.x;
  if (bid < 4096) {
    int i = bid * 256 + threadIdx.x;
    int w = i / n4each;
    int j = i - w * n4each;
    const float4* src = (w == 0) ? w0 : (w == 1) ? w1 : (w == 2) ? w2 : w3;
    float sc = (w == 0) ? scale0 : 1.0f;
    float4 v = src[j];
    bf16x4 o;
    o[0] = (bf16)(v.x * sc);
    o[1] = (bf16)(v.y * sc);
    o[2] = (bf16)(v.z * sc);
    o[3] = (bf16)(v.w * sc);
    wout[i] = o;
  } else if (bid < 4128) {
    int i = (bid - 4096) * 256 + threadIdx.x;
    if (i < nmask) mb[i] = m[i] ? 0.0f : -3e38f;
  } else {
    int i = threadIdx.x;
    if (i < 128) {
      const int* p = m + i * 64;
      int all1 = 1;
#pragma unroll
      for (int j = 0; j < 64; j += 4) {
        int4 v = *(const int4*)(p + j);
        all1 &= (v.x && v.y && v.z && v.w) ? 1 : 0;
      }
      unsigned long long bal = __ballot(all1);
      int wv = i >> 6, lane = i & 63;
      if (lane == 0) {
        cleanw[2 * wv] = (uint)bal;
        cleanw[2 * wv + 1] = (uint)(bal >> 32);
      }
    }
  }
}

// ======== shared GEMM inner loop (R15/R17-proven, byte-identical) ========
// 3-buffer depth-2 counted-vmcnt pipeline + both-sides LDS slot swizzle.
#define GEMM_CORE(Aptr, Bptr, KK)                                          \
  const int sRow = wv * 16 + (lane >> 2);                                  \
  const int sK = ((lane & 3) ^ ((lane >> 3) & 3)) * 8;                     \
  const bf16* aj0 = (Aptr) + (long)(rowBase + sRow) * (KK) + sK;           \
  const bf16* aj1 = aj0 + 64L * (KK);                                      \
  const bf16* bj0 = (Bptr) + (long)(colBase + sRow) * (KK) + sK;           \
  const bf16* bj1 = bj0 + 64L * (KK);                                      \
  f32x4 acc[4][4] = {};                                                    \
  const int gs = (g ^ ((r >> 1) & 3)) * 8;                                 \
  GSTAGE(0, 0);                                                            \
  GSTAGE(1, 32);                                                           \
  int cur = 0, nxt2 = 2;                                                   \
  for (int k0 = 0; k0 < (KK); k0 += 32) {                                  \
    if (k0 + 32 < (KK)) {                                                  \
      asm volatile("s_waitcnt vmcnt(4)" ::: "memory");                     \
    } else {                                                               \
      asm volatile("s_waitcnt vmcnt(0)" ::: "memory");                     \
    }                                                                      \
    BARRIER();                                                             \
    __builtin_amdgcn_sched_barrier(0);                                     \
    if (k0 + 64 < (KK)) GSTAGE(nxt2, k0 + 64);                             \
    const bf16* Ac = As0 + cur * 4096;                                     \
    const bf16* Bc = Bs0 + cur * 4096;                                     \
    bf16x8 af[4], bfr[4];                                                  \
    _Pragma("unroll") for (int m = 0; m < 4; m++)                          \
        af[m] = *(const bf16x8*)(Ac + (wr * 64 + m * 16 + r) * 32 + gs);   \
    _Pragma("unroll") for (int n = 0; n < 4; n++)                          \
        bfr[n] = *(const bf16x8*)(Bc + (wc * 64 + n * 16 + r) * 32 + gs);  \
    __builtin_amdgcn_s_setprio(1);                                         \
    _Pragma("unroll") for (int m = 0; m < 4; m++)                          \
        _Pragma("unroll") for (int n = 0; n < 4; n++)                      \
            acc[m][n] = mfma16(af[m], bfr[n], acc[m][n]);                  \
    __builtin_amdgcn_s_setprio(0);                                         \
    cur = (cur == 2) ? 0 : cur + 1;                                        \
    nxt2 = (nxt2 == 2) ? 0 : nxt2 + 1;                                     \
  }

#define GSTAGE(bi, kk)                                      \
  do {                                                      \
    gload_lds16(aj0 + (kk), As0 + (bi) * 4096 + wv * 512);  \
    gload_lds16(aj1 + (kk), As0 + (bi) * 4096 + 2048 + wv * 512); \
    gload_lds16(bj0 + (kk), Bs0 + (bi) * 4096 + wv * 512);  \
    gload_lds16(bj1 + (kk), Bs0 + (bi) * 4096 + 2048 + wv * 512); \
  } while (0)

// ---- z-fused Q&K projection: one launch, grid 1024 (z = wg>>9) ----
__global__ __launch_bounds__(256) void gemm_qk(
    const bf16* __restrict__ Aq, const bf16* __restrict__ Ak,
    const bf16* __restrict__ Wqk, bf16* __restrict__ Qb, bf16* __restrict__ Kb) {
  __shared__ bf16 As[3][4096];
  __shared__ bf16 Bs[3][4096];
  bf16* As0 = &As[0][0];
  bf16* Bs0 = &Bs[0][0];
  const int tid = threadIdx.x;
  const int lane = tid & 63, wv = tid >> 6;
  const int wr = wv >> 1, wc = wv & 1;
  const int g = lane >> 4, r = lane & 15;
  const int bid = blockIdx.x;
  const int wg = (bid & 7) * 128 + (bid >> 3);  // 1024 = 8*128, bijective
  const int z = wg >> 9;
  const int t5 = wg & 511;
  const int colBase = (t5 & 7) * 128;
  const int rowBase = (t5 >> 3) * 128;
  const bf16* A = z ? Ak : Aq;
  const bf16* Bw = Wqk + (long)z * ND * ND;

  GEMM_CORE(A, Bw, ND)

  bf16* C = z ? Kb : Qb;
#pragma unroll
  for (int m = 0; m < 4; m++)
#pragma unroll
    for (int n = 0; n < 4; n++)
#pragma unroll
      for (int q = 0; q < 4; q++) {
        int row = rowBase + wr * 64 + m * 16 + 4 * g + q;
        int col = colBase + wc * 64 + n * 16 + r;
        C[(long)row * ND + col] = (bf16)acc[m][n][q];
      }
}

// ---- V projection (EPI=1: transposed write) / out-proj (EPI=2: GELU) ----
template <int EPI>
__global__ __launch_bounds__(256) void gemm8(
    const bf16* __restrict__ A, const bf16* __restrict__ Bw,
    bf16* __restrict__ Cb, float* __restrict__ Cf,
    const float* __restrict__ bias, int M, int N, int K) {
  __shared__ bf16 As[3][4096];
  __shared__ bf16 Bs[3][4096];
  bf16* As0 = &As[0][0];
  bf16* Bs0 = &Bs[0][0];
  const int tid = threadIdx.x;
  const int lane = tid & 63, wv = tid >> 6;
  const int wr = wv >> 1, wc = wv & 1;
  const int g = lane >> 4, r = lane & 15;
  const int nx = N >> 7;
  const int chunk = gridDim.x >> 3;
  const int bid = blockIdx.x;
  const int wg = (bid & 7) * chunk + (bid >> 3);
  const int colBase = (wg % nx) * 128;
  const int rowBase = (wg / nx) * 128;

  GEMM_CORE(A, Bw, K)

  if (EPI == 1) {
    // V transposed: Vt[bh][d][s]; s = (rowBase&2047) + wr*64 + m*16 + 4g + q
    const int b = rowBase >> 11;
    const int sbase = (rowBase & 2047) + wr * 64;
#pragma unroll
    for (int m = 0; m < 4; m++) {
#pragma unroll
      for (int n = 0; n < 4; n++) {
        int col = colBase + wc * 64 + n * 16 + r;
        int h = col >> 6, d = col & 63;
        bf16x4 pk;
#pragma unroll
        for (int q = 0; q < 4; q++) pk[q] = (bf16)acc[m][n][q];
        *(bf16x4*)(Cb + ((long)(b * NHH + h) * NHD + d) * NS + sbase + m * 16 + 4 * g) = pk;
      }
    }
  } else {
#pragma unroll
    for (int m = 0; m < 4; m++)
#pragma unroll
      for (int n = 0; n < 4; n++)
#pragma unroll
        for (int q = 0; q < 4; q++) {
          int row = rowBase + wr * 64 + m * 16 + 4 * g + q;
          int col = colBase + wc * 64 + n * 16 + r;
          float v = acc[m][n][q] + bias[col];
          v = 0.5f * v * (1.0f + erff(v * 0.70710678118654752f));
          Cf[(long)row * N + col] = v;
        }
  }
}

// ------- flash attention: 8-wave, swapped-operand, shift-free softmax ----
// (R15/R17-proven, unchanged.)
__global__ __launch_bounds__(512) void attn_fwd4(
    const bf16* __restrict__ Q, const bf16* __restrict__ K,
    const bf16* __restrict__ Vt, const float* __restrict__ mbias,
    const uint* __restrict__ cleanw, bf16* __restrict__ ctx) {
  __shared__ bf16 Ks[3][64 * 64];
  __shared__ bf16 Vs[3][64 * 64];
  bf16* Ks0 = &Ks[0][0];
  bf16* Vs0 = &Vs[0][0];
  const int tid = threadIdx.x;
  const int lane = tid & 63, wv = tid >> 6;
  const int ql = lane & 31, hi = lane >> 5;
  const int g = blockIdx.x;
  const int gx = (g & 63) >> 3;
  const int bh = ((g >> 6) << 3) | (g & 7);
  const int b = bh >> 4, h = bh & 15;
  const int q0 = gx * 256 + wv * 32;

  const bf16* Qp = Q + ((long)(b * NS + q0 + ql)) * ND + h * NHD;
  const bf16* Kp = K + ((long)b * NS) * ND + h * NHD;
  const bf16* Vp = Vt + (long)bh * NHD * NS;
  const float* mbp = mbias + b * NS;
  const uint cw = cleanw[b];

  bf16x8 qf[4];
#pragma unroll
  for (int cd = 0; cd < 4; cd++)
    qf[cd] = *(const bf16x8*)(Qp + cd * 16 + hi * 8);

  bf16x8 ones;
#pragma unroll
  for (int i = 0; i < 8; i++) ones[i] = (bf16)1.0f;

  f32x16 o[2] = {};
  f32x16 ldn = {};

  const int Lrow = wv * 8 + (lane >> 3);
  const int scb = ((lane & 7) * 16) ^ ((Lrow & 7) << 4);
  const bf16* kS = Kp + (long)Lrow * ND + (scb >> 1);
  const bf16* vS = Vp + (long)Lrow * NS + (scb >> 1);

#define ASTAGE(bi, sv)                                        \
  do {                                                        \
    gload_lds16(kS + (long)(sv) * ND, Ks0 + (bi) * 4096 + wv * 512); \
    gload_lds16(vS + (sv), Vs0 + (bi) * 4096 + wv * 512);     \
  } while (0)

  const int swz = (ql & 7) << 4;

  ASTAGE(0, 0);
  int cur = 0, nxt = 1;

  for (int s0 = 0; s0 < NS; s0 += 64) {
    if (s0 + 64 < NS) {
      ASTAGE(nxt, s0 + 64);
      asm volatile("s_waitcnt vmcnt(2)" ::: "memory");
    } else {
      asm volatile("s_waitcnt vmcnt(0)" ::: "memory");
    }
    BARRIER();
    __builtin_amdgcn_sched_barrier(0);
    const char* KsB = (const char*)(Ks0 + cur * 4096);
    const char* VsB = (const char*)(Vs0 + cur * 4096);

    f32x16 st0 = {}, st1 = {};
    __builtin_amdgcn_s_setprio(1);
#pragma unroll
    for (int cd = 0; cd < 4; cd++) {
      bf16x8 kf0 = *(const bf16x8*)(KsB + ql * 128 + ((cd * 32 + hi * 16) ^ swz));
      st0 = mfma32(kf0, qf[cd], st0);
      bf16x8 kf1 = *(const bf16x8*)(KsB + (32 + ql) * 128 + ((cd * 32 + hi * 16) ^ swz));
      st1 = mfma32(kf1, qf[cd], st1);
    }
    __builtin_amdgcn_s_setprio(0);

    if (!((cw >> (s0 >> 6)) & 1)) {
#pragma unroll
      for (int t = 0; t < 4; t++) {
        float4 m0 = *(const float4*)(mbp + s0 + t * 8 + hi * 4);
        st0[4 * t + 0] += m0.x;
        st0[4 * t + 1] += m0.y;
        st0[4 * t + 2] += m0.z;
        st0[4 * t + 3] += m0.w;
        float4 m1 = *(const float4*)(mbp + s0 + 32 + t * 8 + hi * 4);
        st1[4 * t + 0] += m1.x;
        st1[4 * t + 1] += m1.y;
        st1[4 * t + 2] += m1.z;
        st1[4 * t + 3] += m1.w;
      }
    }

#pragma unroll
    for (int i = 0; i < 16; i++) {
      st0[i] = expv(st0[i]);
      st1[i] = expv(st1[i]);
    }

    union {
      uint u[16];
      bf16x8 f[4];
    } pw;
    {
      uint c0 = cvtpk(st0[0], st0[1]), c1 = cvtpk(st0[4], st0[5]);
      swap32u(c0, c1);
      uint d0 = cvtpk(st0[2], st0[3]), d1 = cvtpk(st0[6], st0[7]);
      swap32u(d0, d1);
      pw.u[0] = c0; pw.u[1] = d0; pw.u[2] = c1; pw.u[3] = d1;
      uint e0 = cvtpk(st0[8], st0[9]), e1 = cvtpk(st0[12], st0[13]);
      swap32u(e0, e1);
      uint f0 = cvtpk(st0[10], st0[11]), f1 = cvtpk(st0[14], st0[15]);
      swap32u(f0, f1);
      pw.u[4] = e0; pw.u[5] = f0; pw.u[6] = e1; pw.u[7] = f1;
    }
    {
      uint c0 = cvtpk(st1[0], st1[1]), c1 = cvtpk(st1[4], st1[5]);
      swap32u(c0, c1);
      uint d0 = cvtpk(st1[2], st1[3]), d1 = cvtpk(st1[6], st1[7]);
      swap32u(d0, d1);
      pw.u[8] = c0; pw.u[9] = d0; pw.u[10] = c1; pw.u[11] = d1;
      uint e0 = cvtpk(st1[8], st1[9]), e1 = cvtpk(st1[12], st1[13]);
      swap32u(e0, e1);
      uint f0 = cvtpk(st1[10], st1[11]), f1 = cvtpk(st1[14], st1[15]);
      swap32u(f0, f1);
      pw.u[12] = e0; pw.u[13] = f0; pw.u[14] = e1; pw.u[15] = f1;
    }

    __builtin_amdgcn_s_setprio(1);
#pragma unroll
    for (int dt = 0; dt < 2; dt++) {
#pragma unroll
      for (int ck = 0; ck < 4; ck++) {
        bf16x8 vf = *(const bf16x8*)(VsB + (dt * 32 + ql) * 128 +
                                     ((ck * 32 + hi * 16) ^ swz));
        o[dt] = mfma32(vf, pw.f[ck], o[dt]);
      }
    }
#pragma unroll
    for (int ck = 0; ck < 4; ck++) ldn = mfma32(ones, pw.f[ck], ldn);
    __builtin_amdgcn_s_setprio(0);
    cur = nxt;
    nxt = (nxt == 2) ? 0 : nxt + 1;
  }
#undef ASTAGE

  const float invL = 1.0f / ldn[0];
  bf16* op = ctx + ((long)(b * NS + q0 + ql)) * ND + h * NHD;
#pragma unroll
  for (int dt = 0; dt < 2; dt++) {
#pragma unroll
    for (int t = 0; t < 4; t++) {
      bf16x4 pk;
#pragma unroll
      for (int i = 0; i < 4; i++) pk[i] = (bf16)(o[dt][t * 4 + i] * invL);
      *(bf16x4*)(op + dt * 32 + t * 8 + hi * 4) = pk;
    }
  }
}

extern "C" void kernel_launch(void* const* d_in, const int* in_sizes, int n_in,
                              void* d_out, int out_size, void* d_ws, size_t ws_size,
                              hipStream_t stream) {
  const float* value = (const float*)d_in[0];
  const float* key_t = (const float*)d_in[1];
  const float* query = (const float*)d_in[2];
  const int* mask = (const int*)d_in[3];
  const float* W_q = (const float*)d_in[4];
  const float* W_k = (const float*)d_in[5];
  const float* W_v = (const float*)d_in[6];
  const float* W_o = (const float*)d_in[7];
  const float* b_o = (const float*)d_in[8];
  float* out = (float*)d_out;

  char* ws = (char*)d_ws;
  bf16* Axb = (bf16*)(ws + 0);               // 16MB: query-bf16 -> value-bf16 -> ctx
  bf16* ctx = (bf16*)(ws + 0);
  bf16* wb = (bf16*)(ws + (16UL << 20));     // 8MB: wq, wk, wv, wo
  bf16* Qb = (bf16*)(ws + (24UL << 20));     // 16MB
  bf16* Kb = (bf16*)(ws + (40UL << 20));     // 16MB
  bf16* Vtb = (bf16*)(ws + (56UL << 20));    // 16MB (pre-transposed V)
  bf16* Akb = (bf16*)(ws + (72UL << 20));    // 16MB: key-bf16 (dead after gemm_qk)
  float* mbias = (float*)(ws + (88UL << 20));
  uint* cleanwd = (uint*)(ws + (88UL << 20) + 32768);

  const int nX4 = (NB * NS * ND) / 4;  // 2M float4
  const int nW4 = (ND * ND) / 4;
  // HD^-0.5 * log2(e) folded into W_q -> logits in base-2 units
  const float hscale = 0.125f * 1.44269504088896f;

  prep<<<4129, 256, 0, stream>>>((const float4*)W_q, (const float4*)W_k,
                                 (const float4*)W_v, (const float4*)W_o,
                                 (bf16x4*)wb, hscale, nW4,
                                 mask, mbias, cleanwd, NB * NS);
  bf16* wvb = wb + 2L * ND * ND;
  bf16* wob = wb + 3L * ND * ND;

  const int ggrid = ((NB * NS) / 128) * (ND / 128);  // 64 * 8 = 512

  // query + key converted in ONE launch; Q & K projections z-fused in ONE
  cvt2_bf16<<<2 * nX4 / 256, 256, 0, stream>>>((const float4*)query, (bf16x4*)Axb,
                                               (const float4*)key_t, (bf16x4*)Akb, nX4);
  gemm_qk<<<2 * ggrid, 256, 0, stream>>>(Axb, Akb, wb, Qb, Kb);

  cvt_bf16<<<nX4 / 256, 256, 0, stream>>>((const float4*)value, (bf16x4*)Axb, 1.0f, nX4);
  gemm8<1><<<ggrid, 256, 0, stream>>>(Axb, wvb, Vtb, nullptr, nullptr, NB * NS, ND, ND);

  attn_fwd4<<<512, 512, 0, stream>>>(Qb, Kb, Vtb, mbias, cleanwd, ctx);

  gemm8<2><<<ggrid, 256, 0, stream>>>(ctx, wob, nullptr, out, b_o, NB * NS, ND, ND);
}

// Round 19
// 206.217 us; speedup vs baseline: 2.0742x; 1.0648x over previous
//
#include <hip/hip_runtime.h>
#include <hip/hip_bf16.h>

typedef __bf16 bf16;
typedef __bf16 bf16x8 __attribute__((ext_vector_type(8)));
typedef __bf16 bf16x4 __attribute__((ext_vector_type(4)));
typedef float f32x4 __attribute__((ext_vector_type(4)));
typedef float f32x16 __attribute__((ext_vector_type(16)));
typedef unsigned int uint;

#define NB 4
#define NS 2048
#define ND 1024
#define NHH 16
#define NHD 64

__device__ __forceinline__ void gload_lds16(const void* g, void* l) {
  __builtin_amdgcn_global_load_lds((const __attribute__((address_space(1))) void*)g,
                                   (__attribute__((address_space(3))) void*)l, 16, 0, 0);
}

__device__ __forceinline__ f32x4 mfma16(bf16x8 a, bf16x8 b, f32x4 c) {
  return __builtin_amdgcn_mfma_f32_16x16x32_bf16(a, b, c, 0, 0, 0);
}
__device__ __forceinline__ f32x16 mfma32(bf16x8 a, bf16x8 b, f32x16 c) {
  return __builtin_amdgcn_mfma_f32_32x32x16_bf16(a, b, c, 0, 0, 0);
}
__device__ __forceinline__ uint cvtpk(float lo, float hi) {
  uint r;
  asm("v_cvt_pk_bf16_f32 %0, %1, %2" : "=v"(r) : "v"(lo), "v"(hi));
  return r;
}
__device__ __forceinline__ void swap32u(uint& a, uint& b) {
  asm("v_permlane32_swap_b32 %0, %1" : "+v"(a), "+v"(b));
}
__device__ __forceinline__ float expv(float x) {
  float r;
  asm("v_exp_f32 %0, %1" : "=v"(r) : "v"(x));
  return r;
}
#define BARRIER()                          \
  do {                                     \
    asm volatile("" ::: "memory");         \
    __builtin_amdgcn_s_barrier();          \
    asm volatile("" ::: "memory");         \
  } while (0)

// ---------------- f32 -> bf16 convert (three inputs, one launch) ----------
__global__ __launch_bounds__(256) void cvt3_bf16(const float4* __restrict__ inA,
                                                 bf16x4* __restrict__ outA,
                                                 const float4* __restrict__ inB,
                                                 bf16x4* __restrict__ outB,
                                                 const float4* __restrict__ inC,
                                                 bf16x4* __restrict__ outC,
                                                 int n4each) {
  int i = blockIdx.x * 256 + threadIdx.x;
  int w = i / n4each;
  int j = i - w * n4each;
  const float4* src = (w == 0) ? inA : (w == 1) ? inB : inC;
  bf16x4* dst = (w == 0) ? outA : (w == 1) ? outB : outC;
  float4 v = src[j];
  bf16x4 o;
  o[0] = (bf16)v.x;
  o[1] = (bf16)v.y;
  o[2] = (bf16)v.z;
  o[3] = (bf16)v.w;
  dst[j] = o;
}

// --- fused prep: 4 weights->bf16 | mask->bias | mask->packed clean bits ---
__global__ __launch_bounds__(256) void prep(
    const float4* __restrict__ w0, const float4* __restrict__ w1,
    const float4* __restrict__ w2, const float4* __restrict__ w3,
    bf16x4* __restrict__ wout, float scale0, int n4each,
    const int* __restrict__ m, float* __restrict__ mb,
    uint* __restrict__ cleanw, int nmask) {
  const int bid = blockIdx.x;
  if (bid < 4096) {
    int i = bid * 256 + threadIdx.x;
    int w = i / n4each;
    int j = i - w * n4each;
    const float4* src = (w == 0) ? w0 : (w == 1) ? w1 : (w == 2) ? w2 : w3;
    float sc = (w == 0) ? scale0 : 1.0f;
    float4 v = src[j];
    bf16x4 o;
    o[0] = (bf16)(v.x * sc);
    o[1] = (bf16)(v.y * sc);
    o[2] = (bf16)(v.z * sc);
    o[3] = (bf16)(v.w * sc);
    wout[i] = o;
  } else if (bid < 4128) {
    int i = (bid - 4096) * 256 + threadIdx.x;
    if (i < nmask) mb[i] = m[i] ? 0.0f : -3e38f;
  } else {
    int i = threadIdx.x;
    if (i < 128) {
      const int* p = m + i * 64;
      int all1 = 1;
#pragma unroll
      for (int j = 0; j < 64; j += 4) {
        int4 v = *(const int4*)(p + j);
        all1 &= (v.x && v.y && v.z && v.w) ? 1 : 0;
      }
      unsigned long long bal = __ballot(all1);
      int wv = i >> 6, lane = i & 63;
      if (lane == 0) {
        cleanw[2 * wv] = (uint)bal;
        cleanw[2 * wv + 1] = (uint)(bal >> 32);
      }
    }
  }
}

// ======== shared GEMM inner loop (R15/R17-proven, byte-identical) ========
// 3-buffer depth-2 counted-vmcnt pipeline + both-sides LDS slot swizzle.
#define GEMM_CORE(Aptr, Bptr, KK)                                          \
  const int sRow = wv * 16 + (lane >> 2);                                  \
  const int sK = ((lane & 3) ^ ((lane >> 3) & 3)) * 8;                     \
  const bf16* aj0 = (Aptr) + (long)(rowBase + sRow) * (KK) + sK;           \
  const bf16* aj1 = aj0 + 64L * (KK);                                      \
  const bf16* bj0 = (Bptr) + (long)(colBase + sRow) * (KK) + sK;           \
  const bf16* bj1 = bj0 + 64L * (KK);                                      \
  f32x4 acc[4][4] = {};                                                    \
  const int gs = (g ^ ((r >> 1) & 3)) * 8;                                 \
  GSTAGE(0, 0);                                                            \
  GSTAGE(1, 32);                                                           \
  int cur = 0, nxt2 = 2;                                                   \
  for (int k0 = 0; k0 < (KK); k0 += 32) {                                  \
    if (k0 + 32 < (KK)) {                                                  \
      asm volatile("s_waitcnt vmcnt(4)" ::: "memory");                     \
    } else {                                                               \
      asm volatile("s_waitcnt vmcnt(0)" ::: "memory");                     \
    }                                                                      \
    BARRIER();                                                             \
    __builtin_amdgcn_sched_barrier(0);                                     \
    if (k0 + 64 < (KK)) GSTAGE(nxt2, k0 + 64);                             \
    const bf16* Ac = As0 + cur * 4096;                                     \
    const bf16* Bc = Bs0 + cur * 4096;                                     \
    bf16x8 af[4], bfr[4];                                                  \
    _Pragma("unroll") for (int m = 0; m < 4; m++)                          \
        af[m] = *(const bf16x8*)(Ac + (wr * 64 + m * 16 + r) * 32 + gs);   \
    _Pragma("unroll") for (int n = 0; n < 4; n++)                          \
        bfr[n] = *(const bf16x8*)(Bc + (wc * 64 + n * 16 + r) * 32 + gs);  \
    __builtin_amdgcn_s_setprio(1);                                         \
    _Pragma("unroll") for (int m = 0; m < 4; m++)                          \
        _Pragma("unroll") for (int n = 0; n < 4; n++)                      \
            acc[m][n] = mfma16(af[m], bfr[n], acc[m][n]);                  \
    __builtin_amdgcn_s_setprio(0);                                         \
    cur = (cur == 2) ? 0 : cur + 1;                                        \
    nxt2 = (nxt2 == 2) ? 0 : nxt2 + 1;                                     \
  }

#define GSTAGE(bi, kk)                                      \
  do {                                                      \
    gload_lds16(aj0 + (kk), As0 + (bi) * 4096 + wv * 512);  \
    gload_lds16(aj1 + (kk), As0 + (bi) * 4096 + 2048 + wv * 512); \
    gload_lds16(bj0 + (kk), Bs0 + (bi) * 4096 + wv * 512);  \
    gload_lds16(bj1 + (kk), Bs0 + (bi) * 4096 + 2048 + wv * 512); \
  } while (0)

// ---- z-fused QKV projection: one launch, grid 1536 (z = wg/512) ----
// z==0: Q standard write; z==1: K standard write; z==2: V transposed to
// Vt[bh][d][s] (R15-proven epilogue). High occupancy: 24KB LDS -> up to
// 5-6 blocks/CU resident during the whole QKV phase.
__global__ __launch_bounds__(256) void gemm_qkv3(
    const bf16* __restrict__ Aq, const bf16* __restrict__ Ak,
    const bf16* __restrict__ Av, const bf16* __restrict__ Wb,
    bf16* __restrict__ Qb, bf16* __restrict__ Kb, bf16* __restrict__ Vtb) {
  __shared__ bf16 As[3][4096];
  __shared__ bf16 Bs[3][4096];
  bf16* As0 = &As[0][0];
  bf16* Bs0 = &Bs[0][0];
  const int tid = threadIdx.x;
  const int lane = tid & 63, wv = tid >> 6;
  const int wr = wv >> 1, wc = wv & 1;
  const int g = lane >> 4, r = lane & 15;
  const int bid = blockIdx.x;
  const int wg = (bid & 7) * 192 + (bid >> 3);  // 1536 = 8*192, bijective
  const int z = wg / 512;
  const int t5 = wg - z * 512;
  const int colBase = (t5 & 7) * 128;
  const int rowBase = (t5 >> 3) * 128;
  const bf16* A = (z == 0) ? Aq : (z == 1) ? Ak : Av;
  const bf16* Bw = Wb + (long)z * ND * ND;

  GEMM_CORE(A, Bw, ND)

  if (z <= 1) {
    bf16* C = z ? Kb : Qb;
#pragma unroll
    for (int m = 0; m < 4; m++)
#pragma unroll
      for (int n = 0; n < 4; n++)
#pragma unroll
        for (int q = 0; q < 4; q++) {
          int row = rowBase + wr * 64 + m * 16 + 4 * g + q;
          int col = colBase + wc * 64 + n * 16 + r;
          C[(long)row * ND + col] = (bf16)acc[m][n][q];
        }
  } else {
    // V transposed: Vt[bh][d][s]; s = (rowBase&2047) + wr*64 + m*16 + 4g + q
    const int b = rowBase >> 11;
    const int sbase = (rowBase & 2047) + wr * 64;
#pragma unroll
    for (int m = 0; m < 4; m++) {
#pragma unroll
      for (int n = 0; n < 4; n++) {
        int col = colBase + wc * 64 + n * 16 + r;
        int h = col >> 6, d = col & 63;
        bf16x4 pk;
#pragma unroll
        for (int q = 0; q < 4; q++) pk[q] = (bf16)acc[m][n][q];
        *(bf16x4*)(Vtb + ((long)(b * NHH + h) * NHD + d) * NS + sbase + m * 16 + 4 * g) = pk;
      }
    }
  }
}

// ---- out-projection GEMM: C = A @ Wo^T + bias, exact-erf GELU, f32 out ----
__global__ __launch_bounds__(256) void gemm_out(
    const bf16* __restrict__ A, const bf16* __restrict__ Bw,
    float* __restrict__ Cf, const float* __restrict__ bias, int M, int N, int K) {
  __shared__ bf16 As[3][4096];
  __shared__ bf16 Bs[3][4096];
  bf16* As0 = &As[0][0];
  bf16* Bs0 = &Bs[0][0];
  const int tid = threadIdx.x;
  const int lane = tid & 63, wv = tid >> 6;
  const int wr = wv >> 1, wc = wv & 1;
  const int g = lane >> 4, r = lane & 15;
  const int nx = N >> 7;
  const int chunk = gridDim.x >> 3;
  const int bid = blockIdx.x;
  const int wg = (bid & 7) * chunk + (bid >> 3);
  const int colBase = (wg % nx) * 128;
  const int rowBase = (wg / nx) * 128;

  GEMM_CORE(A, Bw, K)

#pragma unroll
  for (int m = 0; m < 4; m++)
#pragma unroll
    for (int n = 0; n < 4; n++)
#pragma unroll
      for (int q = 0; q < 4; q++) {
        int row = rowBase + wr * 64 + m * 16 + 4 * g + q;
        int col = colBase + wc * 64 + n * 16 + r;
        float v = acc[m][n][q] + bias[col];
        v = 0.5f * v * (1.0f + erff(v * 0.70710678118654752f));
        Cf[(long)row * N + col] = v;
      }
}

// ------- flash attention: 8-wave, swapped-operand, shift-free softmax ----
// (R15/R17-proven, unchanged.)
__global__ __launch_bounds__(512) void attn_fwd4(
    const bf16* __restrict__ Q, const bf16* __restrict__ K,
    const bf16* __restrict__ Vt, const float* __restrict__ mbias,
    const uint* __restrict__ cleanw, bf16* __restrict__ ctx) {
  __shared__ bf16 Ks[3][64 * 64];
  __shared__ bf16 Vs[3][64 * 64];
  bf16* Ks0 = &Ks[0][0];
  bf16* Vs0 = &Vs[0][0];
  const int tid = threadIdx.x;
  const int lane = tid & 63, wv = tid >> 6;
  const int ql = lane & 31, hi = lane >> 5;
  const int g = blockIdx.x;
  const int gx = (g & 63) >> 3;
  const int bh = ((g >> 6) << 3) | (g & 7);
  const int b = bh >> 4, h = bh & 15;
  const int q0 = gx * 256 + wv * 32;

  const bf16* Qp = Q + ((long)(b * NS + q0 + ql)) * ND + h * NHD;
  const bf16* Kp = K + ((long)b * NS) * ND + h * NHD;
  const bf16* Vp = Vt + (long)bh * NHD * NS;
  const float* mbp = mbias + b * NS;
  const uint cw = cleanw[b];

  bf16x8 qf[4];
#pragma unroll
  for (int cd = 0; cd < 4; cd++)
    qf[cd] = *(const bf16x8*)(Qp + cd * 16 + hi * 8);

  bf16x8 ones;
#pragma unroll
  for (int i = 0; i < 8; i++) ones[i] = (bf16)1.0f;

  f32x16 o[2] = {};
  f32x16 ldn = {};

  const int Lrow = wv * 8 + (lane >> 3);
  const int scb = ((lane & 7) * 16) ^ ((Lrow & 7) << 4);
  const bf16* kS = Kp + (long)Lrow * ND + (scb >> 1);
  const bf16* vS = Vp + (long)Lrow * NS + (scb >> 1);

#define ASTAGE(bi, sv)                                        \
  do {                                                        \
    gload_lds16(kS + (long)(sv) * ND, Ks0 + (bi) * 4096 + wv * 512); \
    gload_lds16(vS + (sv), Vs0 + (bi) * 4096 + wv * 512);     \
  } while (0)

  const int swz = (ql & 7) << 4;

  ASTAGE(0, 0);
  int cur = 0, nxt = 1;

  for (int s0 = 0; s0 < NS; s0 += 64) {
    if (s0 + 64 < NS) {
      ASTAGE(nxt, s0 + 64);
      asm volatile("s_waitcnt vmcnt(2)" ::: "memory");
    } else {
      asm volatile("s_waitcnt vmcnt(0)" ::: "memory");
    }
    BARRIER();
    __builtin_amdgcn_sched_barrier(0);
    const char* KsB = (const char*)(Ks0 + cur * 4096);
    const char* VsB = (const char*)(Vs0 + cur * 4096);

    f32x16 st0 = {}, st1 = {};
    __builtin_amdgcn_s_setprio(1);
#pragma unroll
    for (int cd = 0; cd < 4; cd++) {
      bf16x8 kf0 = *(const bf16x8*)(KsB + ql * 128 + ((cd * 32 + hi * 16) ^ swz));
      st0 = mfma32(kf0, qf[cd], st0);
      bf16x8 kf1 = *(const bf16x8*)(KsB + (32 + ql) * 128 + ((cd * 32 + hi * 16) ^ swz));
      st1 = mfma32(kf1, qf[cd], st1);
    }
    __builtin_amdgcn_s_setprio(0);

    if (!((cw >> (s0 >> 6)) & 1)) {
#pragma unroll
      for (int t = 0; t < 4; t++) {
        float4 m0 = *(const float4*)(mbp + s0 + t * 8 + hi * 4);
        st0[4 * t + 0] += m0.x;
        st0[4 * t + 1] += m0.y;
        st0[4 * t + 2] += m0.z;
        st0[4 * t + 3] += m0.w;
        float4 m1 = *(const float4*)(mbp + s0 + 32 + t * 8 + hi * 4);
        st1[4 * t + 0] += m1.x;
        st1[4 * t + 1] += m1.y;
        st1[4 * t + 2] += m1.z;
        st1[4 * t + 3] += m1.w;
      }
    }

#pragma unroll
    for (int i = 0; i < 16; i++) {
      st0[i] = expv(st0[i]);
      st1[i] = expv(st1[i]);
    }

    union {
      uint u[16];
      bf16x8 f[4];
    } pw;
    {
      uint c0 = cvtpk(st0[0], st0[1]), c1 = cvtpk(st0[4], st0[5]);
      swap32u(c0, c1);
      uint d0 = cvtpk(st0[2], st0[3]), d1 = cvtpk(st0[6], st0[7]);
      swap32u(d0, d1);
      pw.u[0] = c0; pw.u[1] = d0; pw.u[2] = c1; pw.u[3] = d1;
      uint e0 = cvtpk(st0[8], st0[9]), e1 = cvtpk(st0[12], st0[13]);
      swap32u(e0, e1);
      uint f0 = cvtpk(st0[10], st0[11]), f1 = cvtpk(st0[14], st0[15]);
      swap32u(f0, f1);
      pw.u[4] = e0; pw.u[5] = f0; pw.u[6] = e1; pw.u[7] = f1;
    }
    {
      uint c0 = cvtpk(st1[0], st1[1]), c1 = cvtpk(st1[4], st1[5]);
      swap32u(c0, c1);
      uint d0 = cvtpk(st1[2], st1[3]), d1 = cvtpk(st1[6], st1[7]);
      swap32u(d0, d1);
      pw.u[8] = c0; pw.u[9] = d0; pw.u[10] = c1; pw.u[11] = d1;
      uint e0 = cvtpk(st1[8], st1[9]), e1 = cvtpk(st1[12], st1[13]);
      swap32u(e0, e1);
      uint f0 = cvtpk(st1[10], st1[11]), f1 = cvtpk(st1[14], st1[15]);
      swap32u(f0, f1);
      pw.u[12] = e0; pw.u[13] = f0; pw.u[14] = e1; pw.u[15] = f1;
    }

    __builtin_amdgcn_s_setprio(1);
#pragma unroll
    for (int dt = 0; dt < 2; dt++) {
#pragma unroll
      for (int ck = 0; ck < 4; ck++) {
        bf16x8 vf = *(const bf16x8*)(VsB + (dt * 32 + ql) * 128 +
                                     ((ck * 32 + hi * 16) ^ swz));
        o[dt] = mfma32(vf, pw.f[ck], o[dt]);
      }
    }
#pragma unroll
    for (int ck = 0; ck < 4; ck++) ldn = mfma32(ones, pw.f[ck], ldn);
    __builtin_amdgcn_s_setprio(0);
    cur = nxt;
    nxt = (nxt == 2) ? 0 : nxt + 1;
  }
#undef ASTAGE

  const float invL = 1.0f / ldn[0];
  bf16* op = ctx + ((long)(b * NS + q0 + ql)) * ND + h * NHD;
#pragma unroll
  for (int dt = 0; dt < 2; dt++) {
#pragma unroll
    for (int t = 0; t < 4; t++) {
      bf16x4 pk;
#pragma unroll
      for (int i = 0; i < 4; i++) pk[i] = (bf16)(o[dt][t * 4 + i] * invL);
      *(bf16x4*)(op + dt * 32 + t * 8 + hi * 4) = pk;
    }
  }
}

extern "C" void kernel_launch(void* const* d_in, const int* in_sizes, int n_in,
                              void* d_out, int out_size, void* d_ws, size_t ws_size,
                              hipStream_t stream) {
  const float* value = (const float*)d_in[0];
  const float* key_t = (const float*)d_in[1];
  const float* query = (const float*)d_in[2];
  const int* mask = (const int*)d_in[3];
  const float* W_q = (const float*)d_in[4];
  const float* W_k = (const float*)d_in[5];
  const float* W_v = (const float*)d_in[6];
  const float* W_o = (const float*)d_in[7];
  const float* b_o = (const float*)d_in[8];
  float* out = (float*)d_out;

  char* ws = (char*)d_ws;
  bf16* Axb = (bf16*)(ws + 0);               // 16MB: query-bf16; later ctx
  bf16* ctx = (bf16*)(ws + 0);
  bf16* wb = (bf16*)(ws + (16UL << 20));     // 8MB: wq, wk, wv, wo
  bf16* Qb = (bf16*)(ws + (24UL << 20));     // 16MB
  bf16* Kb = (bf16*)(ws + (40UL << 20));     // 16MB
  bf16* Vtb = (bf16*)(ws + (56UL << 20));    // 16MB (pre-transposed V)
  bf16* Akb = (bf16*)(ws + (72UL << 20));    // 16MB: key-bf16
  bf16* Avb = (bf16*)d_out;                  // value-bf16 scratch inside d_out
                                             // (dead before gemm_out writes f32)
  float* mbias = (float*)(ws + (88UL << 20));
  uint* cleanwd = (uint*)(ws + (88UL << 20) + 32768);

  const int nX4 = (NB * NS * ND) / 4;  // 2M float4
  const int nW4 = (ND * ND) / 4;
  // HD^-0.5 * log2(e) folded into W_q -> logits in base-2 units
  const float hscale = 0.125f * 1.44269504088896f;

  prep<<<4129, 256, 0, stream>>>((const float4*)W_q, (const float4*)W_k,
                                 (const float4*)W_v, (const float4*)W_o,
                                 (bf16x4*)wb, hscale, nW4,
                                 mask, mbias, cleanwd, NB * NS);
  bf16* wob = wb + 3L * ND * ND;

  // all three inputs converted in ONE launch
  cvt3_bf16<<<3 * nX4 / 256, 256, 0, stream>>>(
      (const float4*)query, (bf16x4*)Axb,
      (const float4*)key_t, (bf16x4*)Akb,
      (const float4*)value, (bf16x4*)Avb, nX4);

  // all three projections in ONE launch (grid 1536: high residency)
  gemm_qkv3<<<1536, 256, 0, stream>>>(Axb, Akb, Avb, wb, Qb, Kb, Vtb);

  attn_fwd4<<<512, 512, 0, stream>>>(Qb, Kb, Vtb, mbias, cleanwd, ctx);

  gemm_out<<<((NB * NS) / 128) * (ND / 128), 256, 0, stream>>>(
      ctx, wob, out, b_o, NB * NS, ND, ND);
}

// Round 20
// 203.925 us; speedup vs baseline: 2.0976x; 1.0112x over previous
//
#include <hip/hip_runtime.h>
#include <hip/hip_bf16.h>

typedef __bf16 bf16;
typedef __bf16 bf16x8 __attribute__((ext_vector_type(8)));
typedef __bf16 bf16x4 __attribute__((ext_vector_type(4)));
typedef float f32x4 __attribute__((ext_vector_type(4)));
typedef float f32x16 __attribute__((ext_vector_type(16)));
typedef unsigned int uint;

#define NB 4
#define NS 2048
#define ND 1024
#define NHH 16
#define NHD 64

__device__ __forceinline__ void gload_lds16(const void* g, void* l) {
  __builtin_amdgcn_global_load_lds((const __attribute__((address_space(1))) void*)g,
                                   (__attribute__((address_space(3))) void*)l, 16, 0, 0);
}

__device__ __forceinline__ f32x4 mfma16(bf16x8 a, bf16x8 b, f32x4 c) {
  return __builtin_amdgcn_mfma_f32_16x16x32_bf16(a, b, c, 0, 0, 0);
}
__device__ __forceinline__ f32x16 mfma32(bf16x8 a, bf16x8 b, f32x16 c) {
  return __builtin_amdgcn_mfma_f32_32x32x16_bf16(a, b, c, 0, 0, 0);
}
__device__ __forceinline__ uint cvtpk(float lo, float hi) {
  uint r;
  asm("v_cvt_pk_bf16_f32 %0, %1, %2" : "=v"(r) : "v"(lo), "v"(hi));
  return r;
}
__device__ __forceinline__ void swap32u(uint& a, uint& b) {
  asm("v_permlane32_swap_b32 %0, %1" : "+v"(a), "+v"(b));
}
__device__ __forceinline__ float expv(float x) {
  float r;
  asm("v_exp_f32 %0, %1" : "=v"(r) : "v"(x));
  return r;
}
#define BARRIER()                          \
  do {                                     \
    asm volatile("" ::: "memory");         \
    __builtin_amdgcn_s_barrier();          \
    asm volatile("" ::: "memory");         \
  } while (0)

// --- single front-end launch: 3 inputs->bf16 | 4 weights->bf16 | mask ---
// blocks [0, 24576): query/key/value f32->bf16 (8192 blocks each)
// blocks [24576, 28672): weights (scale0 on W_q)
// blocks [28672, 28704): mask -> additive bias
// block  28704: mask -> packed per-batch clean bits
__global__ __launch_bounds__(256) void prep_all(
    const float4* __restrict__ inQ, bf16x4* __restrict__ outQ,
    const float4* __restrict__ inK, bf16x4* __restrict__ outK,
    const float4* __restrict__ inV, bf16x4* __restrict__ outV, int n4x,
    const float4* __restrict__ w0, const float4* __restrict__ w1,
    const float4* __restrict__ w2, const float4* __restrict__ w3,
    bf16x4* __restrict__ wout, float scale0, int n4w,
    const int* __restrict__ m, float* __restrict__ mb,
    uint* __restrict__ cleanw, int nmask) {
  const int bid = blockIdx.x;
  if (bid < 24576) {
    int i = bid * 256 + threadIdx.x;
    int w = i / n4x;
    int j = i - w * n4x;
    const float4* src = (w == 0) ? inQ : (w == 1) ? inK : inV;
    bf16x4* dst = (w == 0) ? outQ : (w == 1) ? outK : outV;
    float4 v = src[j];
    bf16x4 o;
    o[0] = (bf16)v.x;
    o[1] = (bf16)v.y;
    o[2] = (bf16)v.z;
    o[3] = (bf16)v.w;
    dst[j] = o;
  } else if (bid < 28672) {
    int i = (bid - 24576) * 256 + threadIdx.x;
    int w = i / n4w;
    int j = i - w * n4w;
    const float4* src = (w == 0) ? w0 : (w == 1) ? w1 : (w == 2) ? w2 : w3;
    float sc = (w == 0) ? scale0 : 1.0f;
    float4 v = src[j];
    bf16x4 o;
    o[0] = (bf16)(v.x * sc);
    o[1] = (bf16)(v.y * sc);
    o[2] = (bf16)(v.z * sc);
    o[3] = (bf16)(v.w * sc);
    wout[i] = o;
  } else if (bid < 28704) {
    int i = (bid - 28672) * 256 + threadIdx.x;
    if (i < nmask) mb[i] = m[i] ? 0.0f : -3e38f;
  } else {
    int i = threadIdx.x;
    if (i < 128) {
      const int* p = m + i * 64;
      int all1 = 1;
#pragma unroll
      for (int j = 0; j < 64; j += 4) {
        int4 v = *(const int4*)(p + j);
        all1 &= (v.x && v.y && v.z && v.w) ? 1 : 0;
      }
      unsigned long long bal = __ballot(all1);
      int wv = i >> 6, lane = i & 63;
      if (lane == 0) {
        cleanw[2 * wv] = (uint)bal;
        cleanw[2 * wv + 1] = (uint)(bal >> 32);
      }
    }
  }
}

// ======== shared GEMM inner loop (R15/R17-proven, byte-identical) ========
// 3-buffer depth-2 counted-vmcnt pipeline + both-sides LDS slot swizzle.
#define GEMM_CORE(Aptr, Bptr, KK)                                          \
  const int sRow = wv * 16 + (lane >> 2);                                  \
  const int sK = ((lane & 3) ^ ((lane >> 3) & 3)) * 8;                     \
  const bf16* aj0 = (Aptr) + (long)(rowBase + sRow) * (KK) + sK;           \
  const bf16* aj1 = aj0 + 64L * (KK);                                      \
  const bf16* bj0 = (Bptr) + (long)(colBase + sRow) * (KK) + sK;           \
  const bf16* bj1 = bj0 + 64L * (KK);                                      \
  f32x4 acc[4][4] = {};                                                    \
  const int gs = (g ^ ((r >> 1) & 3)) * 8;                                 \
  GSTAGE(0, 0);                                                            \
  GSTAGE(1, 32);                                                           \
  int cur = 0, nxt2 = 2;                                                   \
  for (int k0 = 0; k0 < (KK); k0 += 32) {                                  \
    if (k0 + 32 < (KK)) {                                                  \
      asm volatile("s_waitcnt vmcnt(4)" ::: "memory");                     \
    } else {                                                               \
      asm volatile("s_waitcnt vmcnt(0)" ::: "memory");                     \
    }                                                                      \
    BARRIER();                                                             \
    __builtin_amdgcn_sched_barrier(0);                                     \
    if (k0 + 64 < (KK)) GSTAGE(nxt2, k0 + 64);                             \
    const bf16* Ac = As0 + cur * 4096;                                     \
    const bf16* Bc = Bs0 + cur * 4096;                                     \
    bf16x8 af[4], bfr[4];                                                  \
    _Pragma("unroll") for (int m = 0; m < 4; m++)                          \
        af[m] = *(const bf16x8*)(Ac + (wr * 64 + m * 16 + r) * 32 + gs);   \
    _Pragma("unroll") for (int n = 0; n < 4; n++)                          \
        bfr[n] = *(const bf16x8*)(Bc + (wc * 64 + n * 16 + r) * 32 + gs);  \
    __builtin_amdgcn_s_setprio(1);                                         \
    _Pragma("unroll") for (int m = 0; m < 4; m++)                          \
        _Pragma("unroll") for (int n = 0; n < 4; n++)                      \
            acc[m][n] = mfma16(af[m], bfr[n], acc[m][n]);                  \
    __builtin_amdgcn_s_setprio(0);                                         \
    cur = (cur == 2) ? 0 : cur + 1;                                        \
    nxt2 = (nxt2 == 2) ? 0 : nxt2 + 1;                                     \
  }

#define GSTAGE(bi, kk)                                      \
  do {                                                      \
    gload_lds16(aj0 + (kk), As0 + (bi) * 4096 + wv * 512);  \
    gload_lds16(aj1 + (kk), As0 + (bi) * 4096 + 2048 + wv * 512); \
    gload_lds16(bj0 + (kk), Bs0 + (bi) * 4096 + wv * 512);  \
    gload_lds16(bj1 + (kk), Bs0 + (bi) * 4096 + 2048 + wv * 512); \
  } while (0)

// ---- z-fused QKV projection: one launch, grid 1536 (z = wg/512) ----
__global__ __launch_bounds__(256) void gemm_qkv3(
    const bf16* __restrict__ Aq, const bf16* __restrict__ Ak,
    const bf16* __restrict__ Av, const bf16* __restrict__ Wb,
    bf16* __restrict__ Qb, bf16* __restrict__ Kb, bf16* __restrict__ Vtb) {
  __shared__ bf16 As[3][4096];
  __shared__ bf16 Bs[3][4096];
  bf16* As0 = &As[0][0];
  bf16* Bs0 = &Bs[0][0];
  const int tid = threadIdx.x;
  const int lane = tid & 63, wv = tid >> 6;
  const int wr = wv >> 1, wc = wv & 1;
  const int g = lane >> 4, r = lane & 15;
  const int bid = blockIdx.x;
  const int wg = (bid & 7) * 192 + (bid >> 3);  // 1536 = 8*192, bijective
  const int z = wg / 512;
  const int t5 = wg - z * 512;
  const int colBase = (t5 & 7) * 128;
  const int rowBase = (t5 >> 3) * 128;
  const bf16* A = (z == 0) ? Aq : (z == 1) ? Ak : Av;
  const bf16* Bw = Wb + (long)z * ND * ND;

  GEMM_CORE(A, Bw, ND)

  if (z <= 1) {
    bf16* C = z ? Kb : Qb;
#pragma unroll
    for (int m = 0; m < 4; m++)
#pragma unroll
      for (int n = 0; n < 4; n++)
#pragma unroll
        for (int q = 0; q < 4; q++) {
          int row = rowBase + wr * 64 + m * 16 + 4 * g + q;
          int col = colBase + wc * 64 + n * 16 + r;
          C[(long)row * ND + col] = (bf16)acc[m][n][q];
        }
  } else {
    // V transposed: Vt[bh][d][s]; s = (rowBase&2047) + wr*64 + m*16 + 4g + q
    const int b = rowBase >> 11;
    const int sbase = (rowBase & 2047) + wr * 64;
#pragma unroll
    for (int m = 0; m < 4; m++) {
#pragma unroll
      for (int n = 0; n < 4; n++) {
        int col = colBase + wc * 64 + n * 16 + r;
        int h = col >> 6, d = col & 63;
        bf16x4 pk;
#pragma unroll
        for (int q = 0; q < 4; q++) pk[q] = (bf16)acc[m][n][q];
        *(bf16x4*)(Vtb + ((long)(b * NHH + h) * NHD + d) * NS + sbase + m * 16 + 4 * g) = pk;
      }
    }
  }
}

// ---- out-projection GEMM: C = A @ Wo^T + bias, exact-erf GELU, f32 out ----
__global__ __launch_bounds__(256) void gemm_out(
    const bf16* __restrict__ A, const bf16* __restrict__ Bw,
    float* __restrict__ Cf, const float* __restrict__ bias, int M, int N, int K) {
  __shared__ bf16 As[3][4096];
  __shared__ bf16 Bs[3][4096];
  bf16* As0 = &As[0][0];
  bf16* Bs0 = &Bs[0][0];
  const int tid = threadIdx.x;
  const int lane = tid & 63, wv = tid >> 6;
  const int wr = wv >> 1, wc = wv & 1;
  const int g = lane >> 4, r = lane & 15;
  const int nx = N >> 7;
  const int chunk = gridDim.x >> 3;
  const int bid = blockIdx.x;
  const int wg = (bid & 7) * chunk + (bid >> 3);
  const int colBase = (wg % nx) * 128;
  const int rowBase = (wg / nx) * 128;

  GEMM_CORE(A, Bw, K)

#pragma unroll
  for (int m = 0; m < 4; m++)
#pragma unroll
    for (int n = 0; n < 4; n++)
#pragma unroll
      for (int q = 0; q < 4; q++) {
        int row = rowBase + wr * 64 + m * 16 + 4 * g + q;
        int col = colBase + wc * 64 + n * 16 + r;
        float v = acc[m][n][q] + bias[col];
        v = 0.5f * v * (1.0f + erff(v * 0.70710678118654752f));
        Cf[(long)row * N + col] = v;
      }
}

// ------- flash attention: 8-wave, swapped-operand, shift-free softmax ----
// (R15/R17-proven, unchanged.)
__global__ __launch_bounds__(512) void attn_fwd4(
    const bf16* __restrict__ Q, const bf16* __restrict__ K,
    const bf16* __restrict__ Vt, const float* __restrict__ mbias,
    const uint* __restrict__ cleanw, bf16* __restrict__ ctx) {
  __shared__ bf16 Ks[3][64 * 64];
  __shared__ bf16 Vs[3][64 * 64];
  bf16* Ks0 = &Ks[0][0];
  bf16* Vs0 = &Vs[0][0];
  const int tid = threadIdx.x;
  const int lane = tid & 63, wv = tid >> 6;
  const int ql = lane & 31, hi = lane >> 5;
  const int g = blockIdx.x;
  const int gx = (g & 63) >> 3;
  const int bh = ((g >> 6) << 3) | (g & 7);
  const int b = bh >> 4, h = bh & 15;
  const int q0 = gx * 256 + wv * 32;

  const bf16* Qp = Q + ((long)(b * NS + q0 + ql)) * ND + h * NHD;
  const bf16* Kp = K + ((long)b * NS) * ND + h * NHD;
  const bf16* Vp = Vt + (long)bh * NHD * NS;
  const float* mbp = mbias + b * NS;
  const uint cw = cleanw[b];

  bf16x8 qf[4];
#pragma unroll
  for (int cd = 0; cd < 4; cd++)
    qf[cd] = *(const bf16x8*)(Qp + cd * 16 + hi * 8);

  bf16x8 ones;
#pragma unroll
  for (int i = 0; i < 8; i++) ones[i] = (bf16)1.0f;

  f32x16 o[2] = {};
  f32x16 ldn = {};

  const int Lrow = wv * 8 + (lane >> 3);
  const int scb = ((lane & 7) * 16) ^ ((Lrow & 7) << 4);
  const bf16* kS = Kp + (long)Lrow * ND + (scb >> 1);
  const bf16* vS = Vp + (long)Lrow * NS + (scb >> 1);

#define ASTAGE(bi, sv)                                        \
  do {                                                        \
    gload_lds16(kS + (long)(sv) * ND, Ks0 + (bi) * 4096 + wv * 512); \
    gload_lds16(vS + (sv), Vs0 + (bi) * 4096 + wv * 512);     \
  } while (0)

  const int swz = (ql & 7) << 4;

  ASTAGE(0, 0);
  int cur = 0, nxt = 1;

  for (int s0 = 0; s0 < NS; s0 += 64) {
    if (s0 + 64 < NS) {
      ASTAGE(nxt, s0 + 64);
      asm volatile("s_waitcnt vmcnt(2)" ::: "memory");
    } else {
      asm volatile("s_waitcnt vmcnt(0)" ::: "memory");
    }
    BARRIER();
    __builtin_amdgcn_sched_barrier(0);
    const char* KsB = (const char*)(Ks0 + cur * 4096);
    const char* VsB = (const char*)(Vs0 + cur * 4096);

    f32x16 st0 = {}, st1 = {};
    __builtin_amdgcn_s_setprio(1);
#pragma unroll
    for (int cd = 0; cd < 4; cd++) {
      bf16x8 kf0 = *(const bf16x8*)(KsB + ql * 128 + ((cd * 32 + hi * 16) ^ swz));
      st0 = mfma32(kf0, qf[cd], st0);
      bf16x8 kf1 = *(const bf16x8*)(KsB + (32 + ql) * 128 + ((cd * 32 + hi * 16) ^ swz));
      st1 = mfma32(kf1, qf[cd], st1);
    }
    __builtin_amdgcn_s_setprio(0);

    if (!((cw >> (s0 >> 6)) & 1)) {
#pragma unroll
      for (int t = 0; t < 4; t++) {
        float4 m0 = *(const float4*)(mbp + s0 + t * 8 + hi * 4);
        st0[4 * t + 0] += m0.x;
        st0[4 * t + 1] += m0.y;
        st0[4 * t + 2] += m0.z;
        st0[4 * t + 3] += m0.w;
        float4 m1 = *(const float4*)(mbp + s0 + 32 + t * 8 + hi * 4);
        st1[4 * t + 0] += m1.x;
        st1[4 * t + 1] += m1.y;
        st1[4 * t + 2] += m1.z;
        st1[4 * t + 3] += m1.w;
      }
    }

#pragma unroll
    for (int i = 0; i < 16; i++) {
      st0[i] = expv(st0[i]);
      st1[i] = expv(st1[i]);
    }

    union {
      uint u[16];
      bf16x8 f[4];
    } pw;
    {
      uint c0 = cvtpk(st0[0], st0[1]), c1 = cvtpk(st0[4], st0[5]);
      swap32u(c0, c1);
      uint d0 = cvtpk(st0[2], st0[3]), d1 = cvtpk(st0[6], st0[7]);
      swap32u(d0, d1);
      pw.u[0] = c0; pw.u[1] = d0; pw.u[2] = c1; pw.u[3] = d1;
      uint e0 = cvtpk(st0[8], st0[9]), e1 = cvtpk(st0[12], st0[13]);
      swap32u(e0, e1);
      uint f0 = cvtpk(st0[10], st0[11]), f1 = cvtpk(st0[14], st0[15]);
      swap32u(f0, f1);
      pw.u[4] = e0; pw.u[5] = f0; pw.u[6] = e1; pw.u[7] = f1;
    }
    {
      uint c0 = cvtpk(st1[0], st1[1]), c1 = cvtpk(st1[4], st1[5]);
      swap32u(c0, c1);
      uint d0 = cvtpk(st1[2], st1[3]), d1 = cvtpk(st1[6], st1[7]);
      swap32u(d0, d1);
      pw.u[8] = c0; pw.u[9] = d0; pw.u[10] = c1; pw.u[11] = d1;
      uint e0 = cvtpk(st1[8], st1[9]), e1 = cvtpk(st1[12], st1[13]);
      swap32u(e0, e1);
      uint f0 = cvtpk(st1[10], st1[11]), f1 = cvtpk(st1[14], st1[15]);
      swap32u(f0, f1);
      pw.u[12] = e0; pw.u[13] = f0; pw.u[14] = e1; pw.u[15] = f1;
    }

    __builtin_amdgcn_s_setprio(1);
#pragma unroll
    for (int dt = 0; dt < 2; dt++) {
#pragma unroll
      for (int ck = 0; ck < 4; ck++) {
        bf16x8 vf = *(const bf16x8*)(VsB + (dt * 32 + ql) * 128 +
                                     ((ck * 32 + hi * 16) ^ swz));
        o[dt] = mfma32(vf, pw.f[ck], o[dt]);
      }
    }
#pragma unroll
    for (int ck = 0; ck < 4; ck++) ldn = mfma32(ones, pw.f[ck], ldn);
    __builtin_amdgcn_s_setprio(0);
    cur = nxt;
    nxt = (nxt == 2) ? 0 : nxt + 1;
  }
#undef ASTAGE

  const float invL = 1.0f / ldn[0];
  bf16* op = ctx + ((long)(b * NS + q0 + ql)) * ND + h * NHD;
#pragma unroll
  for (int dt = 0; dt < 2; dt++) {
#pragma unroll
    for (int t = 0; t < 4; t++) {
      bf16x4 pk;
#pragma unroll
      for (int i = 0; i < 4; i++) pk[i] = (bf16)(o[dt][t * 4 + i] * invL);
      *(bf16x4*)(op + dt * 32 + t * 8 + hi * 4) = pk;
    }
  }
}

extern "C" void kernel_launch(void* const* d_in, const int* in_sizes, int n_in,
                              void* d_out, int out_size, void* d_ws, size_t ws_size,
                              hipStream_t stream) {
  const float* value = (const float*)d_in[0];
  const float* key_t = (const float*)d_in[1];
  const float* query = (const float*)d_in[2];
  const int* mask = (const int*)d_in[3];
  const float* W_q = (const float*)d_in[4];
  const float* W_k = (const float*)d_in[5];
  const float* W_v = (const float*)d_in[6];
  const float* W_o = (const float*)d_in[7];
  const float* b_o = (const float*)d_in[8];
  float* out = (float*)d_out;

  char* ws = (char*)d_ws;
  bf16* Axb = (bf16*)(ws + 0);               // 16MB: query-bf16; later ctx
  bf16* ctx = (bf16*)(ws + 0);
  bf16* wb = (bf16*)(ws + (16UL << 20));     // 8MB: wq, wk, wv, wo
  bf16* Qb = (bf16*)(ws + (24UL << 20));     // 16MB
  bf16* Kb = (bf16*)(ws + (40UL << 20));     // 16MB
  bf16* Vtb = (bf16*)(ws + (56UL << 20));    // 16MB (pre-transposed V)
  bf16* Akb = (bf16*)(ws + (72UL << 20));    // 16MB: key-bf16
  bf16* Avb = (bf16*)d_out;                  // value-bf16 scratch inside d_out
                                             // (dead before gemm_out writes f32)
  float* mbias = (float*)(ws + (88UL << 20));
  uint* cleanwd = (uint*)(ws + (88UL << 20) + 32768);

  const int nX4 = (NB * NS * ND) / 4;  // 2M float4
  const int nW4 = (ND * ND) / 4;
  // HD^-0.5 * log2(e) folded into W_q -> logits in base-2 units
  const float hscale = 0.125f * 1.44269504088896f;

  // single front-end launch: inputs + weights + mask prep
  prep_all<<<28705, 256, 0, stream>>>(
      (const float4*)query, (bf16x4*)Axb,
      (const float4*)key_t, (bf16x4*)Akb,
      (const float4*)value, (bf16x4*)Avb, nX4,
      (const float4*)W_q, (const float4*)W_k,
      (const float4*)W_v, (const float4*)W_o,
      (bf16x4*)wb, hscale, nW4,
      mask, mbias, cleanwd, NB * NS);
  bf16* wob = wb + 3L * ND * ND;

  // all three projections in ONE launch (grid 1536: high residency)
  gemm_qkv3<<<1536, 256, 0, stream>>>(Axb, Akb, Avb, wb, Qb, Kb, Vtb);

  attn_fwd4<<<512, 512, 0, stream>>>(Qb, Kb, Vtb, mbias, cleanwd, ctx);

  gemm_out<<<((NB * NS) / 128) * (ND / 128), 256, 0, stream>>>(
      ctx, wob, out, b_o, NB * NS, ND, ND);
}